// Round 10
// baseline (225.327 us; speedup 1.0000x reference)
//
#include <hip/hip_runtime.h>
#include <hip/hip_bf16.h>
#include <cstddef>

#define FD 128   // feature dim D == H == 128

typedef __attribute__((ext_vector_type(8))) short short8v;   // 8 bf16 (4 VGPRs)
typedef __attribute__((ext_vector_type(4))) float f32x4;

__device__ __forceinline__ void atomAddF(float* p, float v) {
    unsafeAtomicAdd(p, v);   // HW global_atomic_add_f32 on gfx950
}

__device__ __forceinline__ unsigned short bf16_rne(float x) {
    unsigned u = __float_as_uint(x);
    return (unsigned short)((u + 0x7fffu + ((u >> 16) & 1u)) >> 16);
}

__device__ __forceinline__ float bf_lo(unsigned u) { return __uint_as_float(u << 16); }
__device__ __forceinline__ float bf_hi(unsigned u) { return __uint_as_float(u & 0xffff0000u); }

// ---- one-time W prep: Wq (fp32 [hop][k][col]) -> B-fragment-ordered bf16
// hi/lo.  Fragment order: [hop][kk(4)][ct(8)][lane(64)][j(8)], where the
// element is W[kk*32 + (lane>>4)*8 + j][ct*16 + (lane&15)].
__global__ void wprep_kern(const float* __restrict__ Wq,
                           unsigned short* __restrict__ whi,
                           unsigned short* __restrict__ wlo, int total)
{
    int t = blockIdx.x * blockDim.x + threadIdx.x;
    if (t >= total) return;                 // total = HOPS*2048
    const int hop = t >> 11;
    const int kk  = (t >> 9) & 3;
    const int ct  = (t >> 6) & 7;
    const int l   = t & 63;
    const float* Wh = Wq + (size_t)hop * FD * FD;
    #pragma unroll
    for (int j = 0; j < 8; ++j) {
        float w = Wh[(size_t)(kk * 32 + (l >> 4) * 8 + j) * FD + ct * 16 + (l & 15)];
        unsigned short h = bf16_rne(w);
        float hf = __uint_as_float((unsigned)h << 16);
        whi[(size_t)t * 8 + j] = h;
        wlo[(size_t)t * 8 + j] = bf16_rne(w - hf);
    }
}

// ---- q = x @ Wq[h] + bq[h] via bf16 MFMA.  A = bf16(x): hop 0 reads fp32
// nodes and converts; hops >=1 read LINEAR row-major bf16 x (written by
// gat_node) -> A fragment is one direct 16B load, zero unpack VALU.
// B keeps hi/lo split for fp32-grade weights.  Fused sender-logit
// as_ = q . Wa[:128]  (receiver term cancels in softmax).  q emitted
// bf16-PACKED: q_bfu[row][u] holds cols c0=(u>>4)*32+(u&15) (lo), c0+16 (hi).
// Block: 256 thr = 4 waves; 64 rows/block; each wave a 16-row strip x 128 cols.
__global__ __launch_bounds__(256) void qkern_mfma(
    const float* __restrict__ xin_f, const unsigned short* __restrict__ xin_b,
    const unsigned short* __restrict__ whi, const unsigned short* __restrict__ wlo,
    const float* __restrict__ bq, const float* __restrict__ Wa,
    unsigned* __restrict__ q_bfu, float* __restrict__ as_, int N)
{
    const int lane = threadIdx.x & 63;
    const int w    = threadIdx.x >> 6;          // wave 0..3
    const int rowBase = blockIdx.x * 64 + w * 16;
    if (rowBase >= N) return;
    const int kgrp = lane >> 4;                 // 0..3
    const int cidx = lane & 15;

    // A-row for this lane (clamped; OOB rows guarded at store)
    int arow = rowBase + cidx;
    if (arow >= N) arow = N - 1;

    f32x4 acc[8];
    #pragma unroll
    for (int ct = 0; ct < 8; ++ct) acc[ct] = (f32x4){0.f, 0.f, 0.f, 0.f};

    #pragma unroll
    for (int kk = 0; kk < 4; ++kk) {
        // A fragment: x[arow][kk*32 + kgrp*8 .. +7] as bf16
        short8v a;
        if (xin_b) {                          // wave-uniform branch
            a = *(const short8v*)(xin_b + (size_t)arow * FD + kk * 32 + kgrp * 8);
        } else {
            const float* xp = xin_f + (size_t)arow * FD + kk * 32 + kgrp * 8;
            float4 xa = *(const float4*)(xp);
            float4 xb = *(const float4*)(xp + 4);
            float xv[8] = {xa.x, xa.y, xa.z, xa.w, xb.x, xb.y, xb.z, xb.w};
            #pragma unroll
            for (int j = 0; j < 8; ++j) a[j] = (short)bf16_rne(xv[j]);
        }
        #pragma unroll
        for (int ct = 0; ct < 8; ++ct) {
            const size_t fo = ((size_t)(kk * 8 + ct) * 64 + lane) * 8;
            short8v bhi = *(const short8v*)(whi + fo);
            short8v blo = *(const short8v*)(wlo + fo);
            acc[ct] = __builtin_amdgcn_mfma_f32_16x16x32_bf16(a, bhi, acc[ct], 0, 0, 0);
            acc[ct] = __builtin_amdgcn_mfma_f32_16x16x32_bf16(a, blo, acc[ct], 0, 0, 0);
        }
    }

    // epilogue: bias, packed-bf16 q store, fused as_ dot
    float bqv[8], wav[8];
    #pragma unroll
    for (int ct = 0; ct < 8; ++ct) {
        bqv[ct] = bq[ct * 16 + cidx];
        wav[ct] = Wa[ct * 16 + cidx];
    }
    #pragma unroll
    for (int j = 0; j < 4; ++j) {
        const int row = rowBase + kgrp * 4 + j;      // C/D: row=(lane>>4)*4+reg
        const bool ok = row < N;
        float p = 0.f;
        float vv[8];
        #pragma unroll
        for (int ct = 0; ct < 8; ++ct) {
            vv[ct] = acc[ct][j] + bqv[ct];
            p = fmaf(vv[ct], wav[ct], p);
        }
        if (ok) {
            unsigned* qrow = q_bfu + (size_t)row * 64;
            #pragma unroll
            for (int tp = 0; tp < 4; ++tp) {
                unsigned lo = bf16_rne(vv[2 * tp]);        // col tp*32+cidx
                unsigned hi = bf16_rne(vv[2 * tp + 1]);    // col tp*32+16+cidx
                qrow[tp * 16 + cidx] = lo | (hi << 16);
            }
        }
        p += __shfl_xor(p, 1, 64);
        p += __shfl_xor(p, 2, 64);
        p += __shfl_xor(p, 4, 64);
        p += __shfl_xor(p, 8, 64);
        if (ok && cidx == 0) as_[row] = p;
    }
}

// ---------------- CSR build (once; receivers are hop-invariant) -------------
__global__ void hist_kern(const int* __restrict__ rcv, int* __restrict__ deg, int E) {
    int e = blockIdx.x * blockDim.x + threadIdx.x;
    if (e < E) atomicAdd(&deg[rcv[e]], 1);
}

// hierarchical exclusive scan, phase 1: 2048 elems/block, wave-shuffle scan.
__global__ __launch_bounds__(256) void scan1_kern(
    const int* __restrict__ deg, int* __restrict__ rowptr,
    int* __restrict__ bsum, int N)
{
    const int t = threadIdx.x;
    const int base = blockIdx.x * 2048 + t * 8;
    int v[8]; int s = 0;
    #pragma unroll
    for (int j = 0; j < 8; ++j) {
        v[j] = (base + j < N) ? deg[base + j] : 0;
        s += v[j];
    }
    const int lane = t & 63;
    const int wv = t >> 6;   // 0..3
    int incl = s;
    #pragma unroll
    for (int o = 1; o < 64; o <<= 1) {
        int x = __shfl_up(incl, o, 64);
        if (lane >= o) incl += x;
    }
    __shared__ int wsum[4];
    if (lane == 63) wsum[wv] = incl;
    __syncthreads();
    int woff = 0;
    #pragma unroll
    for (int w = 0; w < 4; ++w) woff += (w < wv) ? wsum[w] : 0;
    int excl = woff + incl - s;
    #pragma unroll
    for (int j = 0; j < 8; ++j) {
        if (base + j < N) rowptr[base + j] = excl;
        excl += v[j];
    }
    if (t == 255) bsum[blockIdx.x] = woff + incl;
}

// phase 2: single wave scans block sums (exclusive, in place); writes rowptr[N].
__global__ void scan2_kern(int* __restrict__ bsum, int* __restrict__ rowptr,
                           int nb, int N, int E)
{
    const int lane = threadIdx.x;   // 64 threads
    int carry = 0;
    for (int c = 0; c < nb; c += 64) {
        int i = c + lane;
        int v = (i < nb) ? bsum[i] : 0;
        int incl = v;
        #pragma unroll
        for (int o = 1; o < 64; o <<= 1) {
            int x = __shfl_up(incl, o, 64);
            if (lane >= o) incl += x;
        }
        if (i < nb) bsum[i] = carry + incl - v;
        carry += __shfl(incl, 63, 64);
    }
    if (lane == 0) rowptr[N] = E;
}

// phase 3: add block offsets; fill cursor copy.
__global__ void scan3_kern(int* __restrict__ rowptr, int* __restrict__ cursor,
                           const int* __restrict__ bsum, int N)
{
    int i = blockIdx.x * blockDim.x + threadIdx.x;
    if (i >= N) return;
    int v = rowptr[i] + bsum[i >> 11];
    rowptr[i] = v;
    cursor[i] = v;
}

__global__ void fill_kern(const int* __restrict__ snd, const int* __restrict__ rcv,
                          int* __restrict__ cursor, int* __restrict__ csr_snd, int E)
{
    int e = blockIdx.x * blockDim.x + threadIdx.x;
    if (e >= E) return;
    int pos = atomicAdd(&cursor[rcv[e]], 1);
    csr_snd[pos] = snd[e];
}

// ---------------- fused pull-based GAT node update --------------------------
// One wave per node. Softmax over as_[senders] (receiver terms cancel).
// deg<=64 path: csr/as_ gathered ONCE into registers. Feature accumulate
// processes 4 EDGES per loop trip: quarter-wave per edge, uint4 (16B) loads.
// Output: LINEAR row-major bf16 (intermediate hops) or fp32 (last, to d_out).
__global__ __launch_bounds__(256) void gat_node_kern(
    const unsigned* __restrict__ q_bfu, const float* __restrict__ as_,
    const int* __restrict__ rowptr, const int* __restrict__ csr_snd,
    float* __restrict__ xout_f, unsigned short* __restrict__ xout_b, int N)
{
    const int lane = threadIdx.x & 63;
    const int n = blockIdx.x * 4 + (threadIdx.x >> 6);
    if (n >= N) return;
    const int start = rowptr[n], end = rowptr[n + 1];
    const int deg = end - start;

    if (deg <= 64) {
        const int i = start + lane;
        const bool valid = i < end;
        const int   s_c = valid ? csr_snd[i] : 0;
        const float a_c = valid ? as_[s_c] : -3.4e38f;
        float m = a_c;
        #pragma unroll
        for (int o = 1; o < 64; o <<= 1) m = fmaxf(m, __shfl_xor(m, o, 64));
        float e = valid ? __expf(a_c - m) : 0.f;
        float d = e;
        #pragma unroll
        for (int o = 1; o < 64; o <<= 1) d += __shfl_xor(d, o, 64);
        const float wgt = e * ((d > 0.f) ? (1.f / d) : 0.f);

        const int qw = lane >> 4;       // quarter-wave = edge slot 0..3
        const int ql = lane & 15;       // lane within quarter
        float4 accLo = make_float4(0.f, 0.f, 0.f, 0.f);
        float4 accHi = make_float4(0.f, 0.f, 0.f, 0.f);
        for (int kb = 0; kb < deg; kb += 4) {
            const int k = kb + qw;
            const int idx = (k < deg) ? k : (deg - 1);
            const int   s    = __shfl(s_c, idx, 64);
            float       coef = __shfl(wgt, idx, 64);
            if (k >= deg) coef = 0.f;
            const uint4 pv = *(const uint4*)(q_bfu + (size_t)s * 64 + 4 * ql);
            accLo.x = fmaf(coef, bf_lo(pv.x), accLo.x);
            accHi.x = fmaf(coef, bf_hi(pv.x), accHi.x);
            accLo.y = fmaf(coef, bf_lo(pv.y), accLo.y);
            accHi.y = fmaf(coef, bf_hi(pv.y), accHi.y);
            accLo.z = fmaf(coef, bf_lo(pv.z), accLo.z);
            accHi.z = fmaf(coef, bf_hi(pv.z), accHi.z);
            accLo.w = fmaf(coef, bf_lo(pv.w), accLo.w);
            accHi.w = fmaf(coef, bf_hi(pv.w), accHi.w);
        }
        // combine the 4 edge slots (lanes ^16, ^32)
        #pragma unroll
        for (int o = 16; o <= 32; o <<= 1) {
            accLo.x += __shfl_xor(accLo.x, o, 64);
            accLo.y += __shfl_xor(accLo.y, o, 64);
            accLo.z += __shfl_xor(accLo.z, o, 64);
            accLo.w += __shfl_xor(accLo.w, o, 64);
            accHi.x += __shfl_xor(accHi.x, o, 64);
            accHi.y += __shfl_xor(accHi.y, o, 64);
            accHi.z += __shfl_xor(accHi.z, o, 64);
            accHi.w += __shfl_xor(accHi.w, o, 64);
        }
        if (qw == 0) {
            // lane ql holds cols c0..c0+3 (lo) and c0+16..+19 (hi)
            const int c0 = (ql >> 2) * 32 + (ql & 3) * 4;
            float4 lo4, hi4;
            lo4.x = accLo.x > 0.f ? accLo.x : 0.01f * accLo.x;
            lo4.y = accLo.y > 0.f ? accLo.y : 0.01f * accLo.y;
            lo4.z = accLo.z > 0.f ? accLo.z : 0.01f * accLo.z;
            lo4.w = accLo.w > 0.f ? accLo.w : 0.01f * accLo.w;
            hi4.x = accHi.x > 0.f ? accHi.x : 0.01f * accHi.x;
            hi4.y = accHi.y > 0.f ? accHi.y : 0.01f * accHi.y;
            hi4.z = accHi.z > 0.f ? accHi.z : 0.01f * accHi.z;
            hi4.w = accHi.w > 0.f ? accHi.w : 0.01f * accHi.w;
            if (xout_b) {
                unsigned short* xr = xout_b + (size_t)n * FD;
                uint2 plo, phi;
                plo.x = (unsigned)bf16_rne(lo4.x) | ((unsigned)bf16_rne(lo4.y) << 16);
                plo.y = (unsigned)bf16_rne(lo4.z) | ((unsigned)bf16_rne(lo4.w) << 16);
                phi.x = (unsigned)bf16_rne(hi4.x) | ((unsigned)bf16_rne(hi4.y) << 16);
                phi.y = (unsigned)bf16_rne(hi4.z) | ((unsigned)bf16_rne(hi4.w) << 16);
                *(uint2*)(xr + c0)      = plo;
                *(uint2*)(xr + c0 + 16) = phi;
            } else {
                *(float4*)(xout_f + (size_t)n * FD + c0)      = lo4;
                *(float4*)(xout_f + (size_t)n * FD + c0 + 16) = hi4;
            }
        }
    } else {
        // general fallback (rare): 3-pass, per-uint lanes
        float m = -3.4e38f;
        for (int i = start + lane; i < end; i += 64) m = fmaxf(m, as_[csr_snd[i]]);
        #pragma unroll
        for (int o = 1; o < 64; o <<= 1) m = fmaxf(m, __shfl_xor(m, o, 64));
        float d = 0.f;
        for (int i = start + lane; i < end; i += 64) d += __expf(as_[csr_snd[i]] - m);
        #pragma unroll
        for (int o = 1; o < 64; o <<= 1) d += __shfl_xor(d, o, 64);
        const float inv = (d > 0.f) ? (1.f / d) : 0.f;
        float accx = 0.f, accy = 0.f;
        for (int i = start; i < end; ++i) {
            const int s = csr_snd[i];
            const float coef = __expf(as_[s] - m) * inv;
            const unsigned pv = q_bfu[(size_t)s * 64 + lane];
            accx = fmaf(coef, bf_lo(pv), accx);
            accy = fmaf(coef, bf_hi(pv), accy);
        }
        accx = accx > 0.f ? accx : 0.01f * accx;
        accy = accy > 0.f ? accy : 0.01f * accy;
        const int c0 = (lane >> 4) * 32 + (lane & 15);
        if (xout_b) {
            xout_b[(size_t)n * FD + c0]      = bf16_rne(accx);
            xout_b[(size_t)n * FD + c0 + 16] = bf16_rne(accy);
        } else {
            xout_f[(size_t)n * FD + c0]      = accx;
            xout_f[(size_t)n * FD + c0 + 16] = accy;
        }
    }
}

// agg[g] = sum of x rows with gidx==g (gidx sorted -> run-length accumulate)
__global__ __launch_bounds__(256) void agg_kern(
    const float* __restrict__ x, const int* __restrict__ gidx,
    float* __restrict__ agg, int N)
{
    const int c  = threadIdx.x & 127;
    const int rl = threadIdx.x >> 7;   // 0..1
    int n   = blockIdx.x * 128 + rl;
    int end = blockIdx.x * 128 + 128;
    if (end > N) end = N;
    float acc = 0.f; int curg = -1;
    for (; n < end; n += 2) {
        int g = gidx[n];
        if (g != curg) {
            if (curg >= 0) atomAddF(&agg[(size_t)curg * FD + c], acc);
            curg = g; acc = 0.f;
        }
        acc += x[(size_t)n * FD + c];
    }
    if (curg >= 0) atomAddF(&agg[(size_t)curg * FD + c], acc);
}

// g_out = concat([agg, globals]) @ Wg + bg.  One block per graph; 256 thr =
// 2 split-K halves x 128 output cols; Wg reads coalesced across cols.
__global__ __launch_bounds__(256) void glob_kern(
    const float* __restrict__ agg, const float* __restrict__ glb,
    const float* __restrict__ Wg, const float* __restrict__ bg,
    float* __restrict__ gout, int G)
{
    __shared__ float xv[256];
    __shared__ float part[128];
    const int g = blockIdx.x;
    const int t = threadIdx.x;
    if (t < 128) xv[t] = agg[(size_t)g * FD + t];
    else         xv[t] = glb[(size_t)g * FD + (t - 128)];
    __syncthreads();
    const int c = t & 127, half = t >> 7;
    const float* __restrict__ W = Wg + (size_t)half * FD * FD;
    const float* __restrict__ xh = xv + half * FD;
    float acc = 0.f;
    #pragma unroll 8
    for (int k = 0; k < FD; ++k)
        acc = fmaf(xh[k], W[(size_t)k * FD + c], acc);
    if (half == 1) part[c] = acc;
    __syncthreads();
    if (half == 0) gout[(size_t)g * FD + c] = acc + part[c] + bg[c];
}

extern "C" void kernel_launch(void* const* d_in, const int* in_sizes, int n_in,
                              void* d_out, int out_size, void* d_ws, size_t ws_size,
                              hipStream_t stream)
{
    const float* nodes    = (const float*)d_in[0];
    const float* globals_ = (const float*)d_in[1];
    const float* Wq       = (const float*)d_in[2];
    const float* bq       = (const float*)d_in[3];
    const float* Wa       = (const float*)d_in[4];
    const float* ba       = (const float*)d_in[5];  (void)ba;  // cancels in softmax
    const float* Wg       = (const float*)d_in[6];
    const float* bg       = (const float*)d_in[7];
    const int* senders    = (const int*)d_in[8];
    const int* receivers  = (const int*)d_in[9];
    const int* gidx       = (const int*)d_in[10];

    const int N    = in_sizes[0] / FD;
    const int G    = in_sizes[1] / FD;
    const int E    = in_sizes[8];
    const int HOPS = in_sizes[3] / FD;
    const int NB   = (N + 2047) / 2048;   // scan blocks

    // workspace layout
    float* ws = (float*)d_ws;
    size_t off = 0;
    unsigned* q_bfu = (unsigned*)ws;  off += (size_t)N * 64;   // packed bf16 q
    unsigned short* xb0 = (unsigned short*)(ws + off); off += (size_t)N * 64; // bf16 x ping
    unsigned short* xb1 = (unsigned short*)(ws + off); off += (size_t)N * 64; // bf16 x pong
    float* agg  = ws + off;        off += (size_t)G * FD;
    float* as_  = ws + off;        off += N;
    int* deg     = (int*)(ws + off); off += N;
    int* rowptr  = (int*)(ws + off); off += N + 1;
    int* cursor  = (int*)(ws + off); off += N;
    int* bsum    = (int*)(ws + off); off += NB;
    int* csr_snd = (int*)(ws + off); off += E;
    off = (off + 3) & ~(size_t)3;                       // 16B-align for short8 loads
    unsigned short* wq_hi = (unsigned short*)(ws + off); off += (size_t)HOPS * 16384 / 2;
    unsigned short* wq_lo = (unsigned short*)(ws + off); off += (size_t)HOPS * 16384 / 2;

    float* xout_final = (float*)d_out;                  // N*FD
    float* gout = (float*)d_out + (size_t)N * FD;       // G*FD

    // ---- one-time prep: CSR (receivers identical across hops) + W bf16 frags
    hipMemsetAsync(deg, 0, (size_t)N * sizeof(int), stream);
    hipMemsetAsync(agg, 0, (size_t)G * FD * sizeof(float), stream);
    hist_kern<<<(E + 255) / 256, 256, 0, stream>>>(receivers, deg, E);
    scan1_kern<<<NB, 256, 0, stream>>>(deg, rowptr, bsum, N);
    scan2_kern<<<1, 64, 0, stream>>>(bsum, rowptr, NB, N, E);
    scan3_kern<<<(N + 255) / 256, 256, 0, stream>>>(rowptr, cursor, bsum, N);
    fill_kern<<<(E + 255) / 256, 256, 0, stream>>>(senders, receivers, cursor, csr_snd, E);
    const int wtot = HOPS * 2048;
    wprep_kern<<<(wtot + 255) / 256, 256, 0, stream>>>(Wq, wq_hi, wq_lo, wtot);

    const float* xin_f = nodes;
    const unsigned short* xin_b = nullptr;
    for (int h = 0; h < HOPS; ++h) {
        const bool last = (h == HOPS - 1);
        unsigned short* xout_b = last ? nullptr : ((xin_b == xb0) ? xb1 : xb0);
        const unsigned short* whi_h = wq_hi + (size_t)h * 16384;
        const unsigned short* wlo_h = wq_lo + (size_t)h * 16384;
        const float* bq_h = bq + (size_t)h * FD;
        const float* Wa_h = Wa + (size_t)h * 2 * FD;

        qkern_mfma<<<(N + 63) / 64, 256, 0, stream>>>(xin_f, xin_b, whi_h, wlo_h,
                                                      bq_h, Wa_h, q_bfu, as_, N);
        gat_node_kern<<<(N + 3) / 4, 256, 0, stream>>>(q_bfu, as_, rowptr, csr_snd,
                                                       last ? xout_final : nullptr,
                                                       xout_b, N);
        xin_f = nullptr;
        xin_b = xout_b;
    }

    agg_kern<<<(N + 127) / 128, 256, 0, stream>>>(xout_final, gidx, agg, N);
    glob_kern<<<G, 256, 0, stream>>>(agg, globals_, Wg, bg, gout, G);
}

// Round 11
// 218.741 us; speedup vs baseline: 1.0301x; 1.0301x over previous
//
#include <hip/hip_runtime.h>
#include <hip/hip_bf16.h>
#include <cstddef>

#define FD 128   // feature dim D == H == 128

typedef __attribute__((ext_vector_type(8))) short short8v;   // 8 bf16 (4 VGPRs)
typedef __attribute__((ext_vector_type(4))) float f32x4;

__device__ __forceinline__ void atomAddF(float* p, float v) {
    unsafeAtomicAdd(p, v);   // HW global_atomic_add_f32 on gfx950
}

__device__ __forceinline__ unsigned short bf16_rne(float x) {
    unsigned u = __float_as_uint(x);
    return (unsigned short)((u + 0x7fffu + ((u >> 16) & 1u)) >> 16);
}

__device__ __forceinline__ float bf_lo(unsigned u) { return __uint_as_float(u << 16); }
__device__ __forceinline__ float bf_hi(unsigned u) { return __uint_as_float(u & 0xffff0000u); }

// ---- one-time W prep: Wq (fp32 [hop][k][col]) -> B-fragment-ordered bf16
// hi/lo.  Fragment order: [hop][kk(4)][ct(8)][lane(64)][j(8)], where the
// element is W[kk*32 + (lane>>4)*8 + j][ct*16 + (lane&15)].
__global__ void wprep_kern(const float* __restrict__ Wq,
                           unsigned short* __restrict__ whi,
                           unsigned short* __restrict__ wlo, int total)
{
    int t = blockIdx.x * blockDim.x + threadIdx.x;
    if (t >= total) return;                 // total = HOPS*2048
    const int hop = t >> 11;
    const int kk  = (t >> 9) & 3;
    const int ct  = (t >> 6) & 7;
    const int l   = t & 63;
    const float* Wh = Wq + (size_t)hop * FD * FD;
    #pragma unroll
    for (int j = 0; j < 8; ++j) {
        float w = Wh[(size_t)(kk * 32 + (l >> 4) * 8 + j) * FD + ct * 16 + (l & 15)];
        unsigned short h = bf16_rne(w);
        float hf = __uint_as_float((unsigned)h << 16);
        whi[(size_t)t * 8 + j] = h;
        wlo[(size_t)t * 8 + j] = bf16_rne(w - hf);
    }
}

// ---- q = xin @ Wq[h] + bq[h] via bf16 MFMA.  A = bf16(x) single fragment
// (q features are bf16-rounded at store anyway — R8 verified absmax
// identical).  B keeps hi/lo split for fp32-grade weights.  Fused
// sender-logit as_ = q . Wa[:128]  (receiver term cancels in softmax).
// q emitted bf16-PACKED: q_bfu[row][u] holds cols c0=(u>>4)*32+(u&15) (lo),
// c0+16 (hi).
// Block: 256 thr = 4 waves; 64 rows/block; each wave a 16-row strip x 128 cols.
__global__ __launch_bounds__(256) void qkern_mfma(
    const float* __restrict__ xin,
    const unsigned short* __restrict__ whi, const unsigned short* __restrict__ wlo,
    const float* __restrict__ bq, const float* __restrict__ Wa,
    unsigned* __restrict__ q_bfu, float* __restrict__ as_, int N)
{
    const int lane = threadIdx.x & 63;
    const int w    = threadIdx.x >> 6;          // wave 0..3
    const int rowBase = blockIdx.x * 64 + w * 16;
    if (rowBase >= N) return;
    const int kgrp = lane >> 4;                 // 0..3
    const int cidx = lane & 15;

    // A-row for this lane (clamped; OOB rows guarded at store)
    int arow = rowBase + cidx;
    if (arow >= N) arow = N - 1;
    const float* __restrict__ xrow = xin + (size_t)arow * FD;

    f32x4 acc[8];
    #pragma unroll
    for (int ct = 0; ct < 8; ++ct) acc[ct] = (f32x4){0.f, 0.f, 0.f, 0.f};

    #pragma unroll
    for (int kk = 0; kk < 4; ++kk) {
        // A fragment: x[arow][kk*32 + kgrp*8 .. +7] -> bf16
        const float* xp = xrow + kk * 32 + kgrp * 8;
        float4 xa = *(const float4*)(xp);
        float4 xb = *(const float4*)(xp + 4);
        float xv[8] = {xa.x, xa.y, xa.z, xa.w, xb.x, xb.y, xb.z, xb.w};
        short8v a;
        #pragma unroll
        for (int j = 0; j < 8; ++j) a[j] = (short)bf16_rne(xv[j]);
        #pragma unroll
        for (int ct = 0; ct < 8; ++ct) {
            const size_t fo = ((size_t)(kk * 8 + ct) * 64 + lane) * 8;
            short8v bhi = *(const short8v*)(whi + fo);
            short8v blo = *(const short8v*)(wlo + fo);
            acc[ct] = __builtin_amdgcn_mfma_f32_16x16x32_bf16(a, bhi, acc[ct], 0, 0, 0);
            acc[ct] = __builtin_amdgcn_mfma_f32_16x16x32_bf16(a, blo, acc[ct], 0, 0, 0);
        }
    }

    // epilogue: bias, packed-bf16 q store, fused as_ dot
    float bqv[8], wav[8];
    #pragma unroll
    for (int ct = 0; ct < 8; ++ct) {
        bqv[ct] = bq[ct * 16 + cidx];
        wav[ct] = Wa[ct * 16 + cidx];
    }
    #pragma unroll
    for (int j = 0; j < 4; ++j) {
        const int row = rowBase + kgrp * 4 + j;      // C/D: row=(lane>>4)*4+reg
        const bool ok = row < N;
        float p = 0.f;
        float vv[8];
        #pragma unroll
        for (int ct = 0; ct < 8; ++ct) {
            vv[ct] = acc[ct][j] + bqv[ct];
            p = fmaf(vv[ct], wav[ct], p);
        }
        if (ok) {
            unsigned* qrow = q_bfu + (size_t)row * 64;
            #pragma unroll
            for (int tp = 0; tp < 4; ++tp) {
                unsigned lo = bf16_rne(vv[2 * tp]);        // col tp*32+cidx
                unsigned hi = bf16_rne(vv[2 * tp + 1]);    // col tp*32+16+cidx
                qrow[tp * 16 + cidx] = lo | (hi << 16);
            }
        }
        p += __shfl_xor(p, 1, 64);
        p += __shfl_xor(p, 2, 64);
        p += __shfl_xor(p, 4, 64);
        p += __shfl_xor(p, 8, 64);
        if (ok && cidx == 0) as_[row] = p;
    }
}

// ---------------- CSR build (once; receivers are hop-invariant) -------------
__global__ void hist_kern(const int* __restrict__ rcv, int* __restrict__ deg, int E) {
    int e = blockIdx.x * blockDim.x + threadIdx.x;
    if (e < E) atomicAdd(&deg[rcv[e]], 1);
}

// hierarchical exclusive scan, phase 1: 2048 elems/block, wave-shuffle scan.
__global__ __launch_bounds__(256) void scan1_kern(
    const int* __restrict__ deg, int* __restrict__ rowptr,
    int* __restrict__ bsum, int N)
{
    const int t = threadIdx.x;
    const int base = blockIdx.x * 2048 + t * 8;
    int v[8]; int s = 0;
    #pragma unroll
    for (int j = 0; j < 8; ++j) {
        v[j] = (base + j < N) ? deg[base + j] : 0;
        s += v[j];
    }
    const int lane = t & 63;
    const int wv = t >> 6;   // 0..3
    int incl = s;
    #pragma unroll
    for (int o = 1; o < 64; o <<= 1) {
        int x = __shfl_up(incl, o, 64);
        if (lane >= o) incl += x;
    }
    __shared__ int wsum[4];
    if (lane == 63) wsum[wv] = incl;
    __syncthreads();
    int woff = 0;
    #pragma unroll
    for (int w = 0; w < 4; ++w) woff += (w < wv) ? wsum[w] : 0;
    int excl = woff + incl - s;
    #pragma unroll
    for (int j = 0; j < 8; ++j) {
        if (base + j < N) rowptr[base + j] = excl;
        excl += v[j];
    }
    if (t == 255) bsum[blockIdx.x] = woff + incl;
}

// phase 2: single wave scans block sums (exclusive, in place); writes rowptr[N].
__global__ void scan2_kern(int* __restrict__ bsum, int* __restrict__ rowptr,
                           int nb, int N, int E)
{
    const int lane = threadIdx.x;   // 64 threads
    int carry = 0;
    for (int c = 0; c < nb; c += 64) {
        int i = c + lane;
        int v = (i < nb) ? bsum[i] : 0;
        int incl = v;
        #pragma unroll
        for (int o = 1; o < 64; o <<= 1) {
            int x = __shfl_up(incl, o, 64);
            if (lane >= o) incl += x;
        }
        if (i < nb) bsum[i] = carry + incl - v;
        carry += __shfl(incl, 63, 64);
    }
    if (lane == 0) rowptr[N] = E;
}

// phase 3: add block offsets; fill cursor copy.
__global__ void scan3_kern(int* __restrict__ rowptr, int* __restrict__ cursor,
                           const int* __restrict__ bsum, int N)
{
    int i = blockIdx.x * blockDim.x + threadIdx.x;
    if (i >= N) return;
    int v = rowptr[i] + bsum[i >> 11];
    rowptr[i] = v;
    cursor[i] = v;
}

__global__ void fill_kern(const int* __restrict__ snd, const int* __restrict__ rcv,
                          int* __restrict__ cursor, int* __restrict__ csr_snd, int E)
{
    int e = blockIdx.x * blockDim.x + threadIdx.x;
    if (e >= E) return;
    int pos = atomicAdd(&cursor[rcv[e]], 1);
    csr_snd[pos] = snd[e];
}

// ---------------- fused pull-based GAT node update --------------------------
// One wave per node. Softmax over as_[senders] (receiver terms cancel).
// deg<=64 path: csr/as_ gathered ONCE into registers; NO max-shift (logits
// are O(5) dots of unit-variance vectors — exp cannot overflow; weights are
// mathematically identical). Feature accumulate: 4 EDGES per trip,
// quarter-wave per edge, uint4 (16B) loads; cross-quarter shfl_xor reduce;
// float4 stores.
__global__ __launch_bounds__(256) void gat_node_kern(
    const unsigned* __restrict__ q_bfu, const float* __restrict__ as_,
    const int* __restrict__ rowptr, const int* __restrict__ csr_snd,
    float* __restrict__ xout, int N)
{
    const int lane = threadIdx.x & 63;
    const int n = blockIdx.x * 4 + (threadIdx.x >> 6);
    if (n >= N) return;
    const int start = rowptr[n], end = rowptr[n + 1];
    const int deg = end - start;

    if (deg <= 64) {
        const int i = start + lane;
        const bool valid = i < end;
        const int   s_c = valid ? csr_snd[i] : 0;
        const float e = valid ? __expf(as_[s_c]) : 0.f;
        float d = e;
        #pragma unroll
        for (int o = 1; o < 64; o <<= 1) d += __shfl_xor(d, o, 64);
        const float wgt = e * ((d > 0.f) ? (1.f / d) : 0.f);

        const int qw = lane >> 4;       // quarter-wave = edge slot 0..3
        const int ql = lane & 15;       // lane within quarter
        float4 accLo = make_float4(0.f, 0.f, 0.f, 0.f);
        float4 accHi = make_float4(0.f, 0.f, 0.f, 0.f);
        for (int kb = 0; kb < deg; kb += 4) {
            const int k = kb + qw;
            const int idx = (k < deg) ? k : (deg - 1);
            const int   s    = __shfl(s_c, idx, 64);
            float       coef = __shfl(wgt, idx, 64);
            if (k >= deg) coef = 0.f;
            const uint4 pv = *(const uint4*)(q_bfu + (size_t)s * 64 + 4 * ql);
            accLo.x = fmaf(coef, bf_lo(pv.x), accLo.x);
            accHi.x = fmaf(coef, bf_hi(pv.x), accHi.x);
            accLo.y = fmaf(coef, bf_lo(pv.y), accLo.y);
            accHi.y = fmaf(coef, bf_hi(pv.y), accHi.y);
            accLo.z = fmaf(coef, bf_lo(pv.z), accLo.z);
            accHi.z = fmaf(coef, bf_hi(pv.z), accHi.z);
            accLo.w = fmaf(coef, bf_lo(pv.w), accLo.w);
            accHi.w = fmaf(coef, bf_hi(pv.w), accHi.w);
        }
        // combine the 4 edge slots (lanes ^16, ^32)
        #pragma unroll
        for (int o = 16; o <= 32; o <<= 1) {
            accLo.x += __shfl_xor(accLo.x, o, 64);
            accLo.y += __shfl_xor(accLo.y, o, 64);
            accLo.z += __shfl_xor(accLo.z, o, 64);
            accLo.w += __shfl_xor(accLo.w, o, 64);
            accHi.x += __shfl_xor(accHi.x, o, 64);
            accHi.y += __shfl_xor(accHi.y, o, 64);
            accHi.z += __shfl_xor(accHi.z, o, 64);
            accHi.w += __shfl_xor(accHi.w, o, 64);
        }
        if (qw == 0) {
            // lane ql holds uints u=4*ql..4*ql+3: lo -> cols c0..c0+3, hi -> +16
            const int c0 = (ql >> 2) * 32 + (ql & 3) * 4;
            float4 lo4, hi4;
            lo4.x = accLo.x > 0.f ? accLo.x : 0.01f * accLo.x;
            lo4.y = accLo.y > 0.f ? accLo.y : 0.01f * accLo.y;
            lo4.z = accLo.z > 0.f ? accLo.z : 0.01f * accLo.z;
            lo4.w = accLo.w > 0.f ? accLo.w : 0.01f * accLo.w;
            hi4.x = accHi.x > 0.f ? accHi.x : 0.01f * accHi.x;
            hi4.y = accHi.y > 0.f ? accHi.y : 0.01f * accHi.y;
            hi4.z = accHi.z > 0.f ? accHi.z : 0.01f * accHi.z;
            hi4.w = accHi.w > 0.f ? accHi.w : 0.01f * accHi.w;
            *(float4*)(xout + (size_t)n * FD + c0)      = lo4;
            *(float4*)(xout + (size_t)n * FD + c0 + 16) = hi4;
        }
    } else {
        // general fallback (rare): 3-pass with max-shift, per-uint lanes
        float m = -3.4e38f;
        for (int i = start + lane; i < end; i += 64) m = fmaxf(m, as_[csr_snd[i]]);
        #pragma unroll
        for (int o = 1; o < 64; o <<= 1) m = fmaxf(m, __shfl_xor(m, o, 64));
        float d = 0.f;
        for (int i = start + lane; i < end; i += 64) d += __expf(as_[csr_snd[i]] - m);
        #pragma unroll
        for (int o = 1; o < 64; o <<= 1) d += __shfl_xor(d, o, 64);
        const float inv = (d > 0.f) ? (1.f / d) : 0.f;
        float accx = 0.f, accy = 0.f;
        for (int i = start; i < end; ++i) {
            const int s = csr_snd[i];
            const float coef = __expf(as_[s] - m) * inv;
            const unsigned pv = q_bfu[(size_t)s * 64 + lane];
            accx = fmaf(coef, bf_lo(pv), accx);
            accy = fmaf(coef, bf_hi(pv), accy);
        }
        accx = accx > 0.f ? accx : 0.01f * accx;
        accy = accy > 0.f ? accy : 0.01f * accy;
        const int c0 = (lane >> 4) * 32 + (lane & 15);
        xout[(size_t)n * FD + c0]      = accx;
        xout[(size_t)n * FD + c0 + 16] = accy;
    }
}

// agg[g] = sum of x rows with gidx==g (gidx sorted -> run-length accumulate)
__global__ __launch_bounds__(256) void agg_kern(
    const float* __restrict__ x, const int* __restrict__ gidx,
    float* __restrict__ agg, int N)
{
    const int c  = threadIdx.x & 127;
    const int rl = threadIdx.x >> 7;   // 0..1
    int n   = blockIdx.x * 128 + rl;
    int end = blockIdx.x * 128 + 128;
    if (end > N) end = N;
    float acc = 0.f; int curg = -1;
    for (; n < end; n += 2) {
        int g = gidx[n];
        if (g != curg) {
            if (curg >= 0) atomAddF(&agg[(size_t)curg * FD + c], acc);
            curg = g; acc = 0.f;
        }
        acc += x[(size_t)n * FD + c];
    }
    if (curg >= 0) atomAddF(&agg[(size_t)curg * FD + c], acc);
}

// g_out = concat([agg, globals]) @ Wg + bg.  One block per graph; 256 thr =
// 2 split-K halves x 128 output cols; Wg reads coalesced across cols.
__global__ __launch_bounds__(256) void glob_kern(
    const float* __restrict__ agg, const float* __restrict__ glb,
    const float* __restrict__ Wg, const float* __restrict__ bg,
    float* __restrict__ gout, int G)
{
    __shared__ float xv[256];
    __shared__ float part[128];
    const int g = blockIdx.x;
    const int t = threadIdx.x;
    if (t < 128) xv[t] = agg[(size_t)g * FD + t];
    else         xv[t] = glb[(size_t)g * FD + (t - 128)];
    __syncthreads();
    const int c = t & 127, half = t >> 7;
    const float* __restrict__ W = Wg + (size_t)half * FD * FD;
    const float* __restrict__ xh = xv + half * FD;
    float acc = 0.f;
    #pragma unroll 8
    for (int k = 0; k < FD; ++k)
        acc = fmaf(xh[k], W[(size_t)k * FD + c], acc);
    if (half == 1) part[c] = acc;
    __syncthreads();
    if (half == 0) gout[(size_t)g * FD + c] = acc + part[c] + bg[c];
}

extern "C" void kernel_launch(void* const* d_in, const int* in_sizes, int n_in,
                              void* d_out, int out_size, void* d_ws, size_t ws_size,
                              hipStream_t stream)
{
    const float* nodes    = (const float*)d_in[0];
    const float* globals_ = (const float*)d_in[1];
    const float* Wq       = (const float*)d_in[2];
    const float* bq       = (const float*)d_in[3];
    const float* Wa       = (const float*)d_in[4];
    const float* ba       = (const float*)d_in[5];  (void)ba;  // cancels in softmax
    const float* Wg       = (const float*)d_in[6];
    const float* bg       = (const float*)d_in[7];
    const int* senders    = (const int*)d_in[8];
    const int* receivers  = (const int*)d_in[9];
    const int* gidx       = (const int*)d_in[10];

    const int N    = in_sizes[0] / FD;
    const int G    = in_sizes[1] / FD;
    const int E    = in_sizes[8];
    const int HOPS = in_sizes[3] / FD;
    const int NB   = (N + 2047) / 2048;   // scan blocks

    // workspace layout
    float* ws = (float*)d_ws;
    size_t off = 0;
    unsigned* q_bfu = (unsigned*)ws;  off += (size_t)N * 64;   // packed bf16 q
    float* xbuf = ws + off;        off += (size_t)N * FD;
    float* agg  = ws + off;        off += (size_t)G * FD;
    float* as_  = ws + off;        off += N;
    int* deg     = (int*)(ws + off); off += N;
    int* rowptr  = (int*)(ws + off); off += N + 1;
    int* cursor  = (int*)(ws + off); off += N;
    int* bsum    = (int*)(ws + off); off += NB;
    int* csr_snd = (int*)(ws + off); off += E;
    off = (off + 3) & ~(size_t)3;                       // 16B-align for short8 loads
    unsigned short* wq_hi = (unsigned short*)(ws + off); off += (size_t)HOPS * 16384 / 2;
    unsigned short* wq_lo = (unsigned short*)(ws + off); off += (size_t)HOPS * 16384 / 2;

    float* xout_final = (float*)d_out;                  // N*FD
    float* gout = (float*)d_out + (size_t)N * FD;       // G*FD

    // ---- one-time prep: CSR (receivers identical across hops) + W bf16 frags
    hipMemsetAsync(deg, 0, (size_t)N * sizeof(int), stream);
    hipMemsetAsync(agg, 0, (size_t)G * FD * sizeof(float), stream);
    hist_kern<<<(E + 255) / 256, 256, 0, stream>>>(receivers, deg, E);
    scan1_kern<<<NB, 256, 0, stream>>>(deg, rowptr, bsum, N);
    scan2_kern<<<1, 64, 0, stream>>>(bsum, rowptr, NB, N, E);
    scan3_kern<<<(N + 255) / 256, 256, 0, stream>>>(rowptr, cursor, bsum, N);
    fill_kern<<<(E + 255) / 256, 256, 0, stream>>>(senders, receivers, cursor, csr_snd, E);
    const int wtot = HOPS * 2048;
    wprep_kern<<<(wtot + 255) / 256, 256, 0, stream>>>(Wq, wq_hi, wq_lo, wtot);

    const float* xin = nodes;
    for (int h = 0; h < HOPS; ++h) {
        float* xout = (h == HOPS - 1) ? xout_final : xbuf;
        const unsigned short* whi_h = wq_hi + (size_t)h * 16384;
        const unsigned short* wlo_h = wq_lo + (size_t)h * 16384;
        const float* bq_h = bq + (size_t)h * FD;
        const float* Wa_h = Wa + (size_t)h * 2 * FD;

        qkern_mfma<<<(N + 63) / 64, 256, 0, stream>>>(xin, whi_h, wlo_h, bq_h,
                                                      Wa_h, q_bfu, as_, N);
        gat_node_kern<<<(N + 3) / 4, 256, 0, stream>>>(q_bfu, as_, rowptr, csr_snd,
                                                       xout, N);
        xin = xout;
    }

    agg_kern<<<(N + 127) / 128, 256, 0, stream>>>(xin, gidx, agg, N);
    glob_kern<<<G, 256, 0, stream>>>(agg, globals_, Wg, bg, gout, G);
}

// Round 12
// 215.397 us; speedup vs baseline: 1.0461x; 1.0155x over previous
//
#include <hip/hip_runtime.h>
#include <hip/hip_bf16.h>
#include <cstddef>

#define FD 128   // feature dim D == H == 128

typedef __attribute__((ext_vector_type(8))) short short8v;   // 8 bf16 (4 VGPRs)
typedef __attribute__((ext_vector_type(4))) float f32x4;

__device__ __forceinline__ void atomAddF(float* p, float v) {
    unsafeAtomicAdd(p, v);   // HW global_atomic_add_f32 on gfx950
}

__device__ __forceinline__ unsigned short bf16_rne(float x) {
    unsigned u = __float_as_uint(x);
    return (unsigned short)((u + 0x7fffu + ((u >> 16) & 1u)) >> 16);
}

__device__ __forceinline__ float bf_lo(unsigned u) { return __uint_as_float(u << 16); }
__device__ __forceinline__ float bf_hi(unsigned u) { return __uint_as_float(u & 0xffff0000u); }

// ---- one-time W prep: Wq (fp32 [hop][k][col]) -> B-fragment-ordered bf16
// hi/lo.  Fragment order: [hop][kk(4)][ct(8)][lane(64)][j(8)], where the
// element is W[kk*32 + (lane>>4)*8 + j][ct*16 + (lane&15)].
__global__ void wprep_kern(const float* __restrict__ Wq,
                           unsigned short* __restrict__ whi,
                           unsigned short* __restrict__ wlo, int total)
{
    int t = blockIdx.x * blockDim.x + threadIdx.x;
    if (t >= total) return;                 // total = HOPS*2048
    const int hop = t >> 11;
    const int kk  = (t >> 9) & 3;
    const int ct  = (t >> 6) & 7;
    const int l   = t & 63;
    const float* Wh = Wq + (size_t)hop * FD * FD;
    #pragma unroll
    for (int j = 0; j < 8; ++j) {
        float w = Wh[(size_t)(kk * 32 + (l >> 4) * 8 + j) * FD + ct * 16 + (l & 15)];
        unsigned short h = bf16_rne(w);
        float hf = __uint_as_float((unsigned)h << 16);
        whi[(size_t)t * 8 + j] = h;
        wlo[(size_t)t * 8 + j] = bf16_rne(w - hf);
    }
}

// ---- q = xin @ Wq[h] + bq[h] via bf16 MFMA.  A = bf16(x) single fragment.
// B hi/lo split for fp32-grade weights.  W-REUSE: each wave computes 32 rows
// (two 16-row A strips) per B-load pair -> 4 MFMAs per 32B of W, halving
// W-load instructions vs the 16-row version (qkern is VMEM-issue-bound).
// Fused sender-logit as_ = q . Wa[:128]  (receiver term cancels in softmax).
// q emitted bf16-PACKED: q_bfu[row][u] holds cols c0=(u>>4)*32+(u&15) (lo),
// c0+16 (hi).
// Block: 256 thr = 4 waves; 128 rows/block.
__global__ __launch_bounds__(256) void qkern_mfma(
    const float* __restrict__ xin,
    const unsigned short* __restrict__ whi, const unsigned short* __restrict__ wlo,
    const float* __restrict__ bq, const float* __restrict__ Wa,
    unsigned* __restrict__ q_bfu, float* __restrict__ as_, int N)
{
    const int lane = threadIdx.x & 63;
    const int w    = threadIdx.x >> 6;          // wave 0..3
    const int rowBase = blockIdx.x * 128 + w * 32;
    if (rowBase >= N) return;
    const int kgrp = lane >> 4;                 // 0..3
    const int cidx = lane & 15;

    // A-rows for the two strips (clamped; OOB rows guarded at store)
    int arow0 = rowBase + cidx;       if (arow0 >= N) arow0 = N - 1;
    int arow1 = rowBase + 16 + cidx;  if (arow1 >= N) arow1 = N - 1;
    const float* __restrict__ xr0 = xin + (size_t)arow0 * FD;
    const float* __restrict__ xr1 = xin + (size_t)arow1 * FD;

    f32x4 acc0[8], acc1[8];
    #pragma unroll
    for (int ct = 0; ct < 8; ++ct) {
        acc0[ct] = (f32x4){0.f, 0.f, 0.f, 0.f};
        acc1[ct] = (f32x4){0.f, 0.f, 0.f, 0.f};
    }

    #pragma unroll
    for (int kk = 0; kk < 4; ++kk) {
        const int ko = kk * 32 + kgrp * 8;
        float4 x0a = *(const float4*)(xr0 + ko);
        float4 x0b = *(const float4*)(xr0 + ko + 4);
        float4 x1a = *(const float4*)(xr1 + ko);
        float4 x1b = *(const float4*)(xr1 + ko + 4);
        float v0[8] = {x0a.x, x0a.y, x0a.z, x0a.w, x0b.x, x0b.y, x0b.z, x0b.w};
        float v1[8] = {x1a.x, x1a.y, x1a.z, x1a.w, x1b.x, x1b.y, x1b.z, x1b.w};
        short8v a0, a1;
        #pragma unroll
        for (int j = 0; j < 8; ++j) {
            a0[j] = (short)bf16_rne(v0[j]);
            a1[j] = (short)bf16_rne(v1[j]);
        }
        #pragma unroll
        for (int ct = 0; ct < 8; ++ct) {
            const size_t fo = ((size_t)(kk * 8 + ct) * 64 + lane) * 8;
            short8v bhi = *(const short8v*)(whi + fo);
            short8v blo = *(const short8v*)(wlo + fo);
            acc0[ct] = __builtin_amdgcn_mfma_f32_16x16x32_bf16(a0, bhi, acc0[ct], 0, 0, 0);
            acc0[ct] = __builtin_amdgcn_mfma_f32_16x16x32_bf16(a0, blo, acc0[ct], 0, 0, 0);
            acc1[ct] = __builtin_amdgcn_mfma_f32_16x16x32_bf16(a1, bhi, acc1[ct], 0, 0, 0);
            acc1[ct] = __builtin_amdgcn_mfma_f32_16x16x32_bf16(a1, blo, acc1[ct], 0, 0, 0);
        }
    }

    // epilogue: bias, packed-bf16 q store, fused as_ dot — per row strip
    float bqv[8], wav[8];
    #pragma unroll
    for (int ct = 0; ct < 8; ++ct) {
        bqv[ct] = bq[ct * 16 + cidx];
        wav[ct] = Wa[ct * 16 + cidx];
    }
    #pragma unroll
    for (int strip = 0; strip < 2; ++strip) {
        const f32x4* acc = strip ? acc1 : acc0;
        const int sbase = rowBase + strip * 16;
        #pragma unroll
        for (int j = 0; j < 4; ++j) {
            const int row = sbase + kgrp * 4 + j;    // C/D: row=(lane>>4)*4+reg
            const bool ok = row < N;
            float p = 0.f;
            float vv[8];
            #pragma unroll
            for (int ct = 0; ct < 8; ++ct) {
                vv[ct] = acc[ct][j] + bqv[ct];
                p = fmaf(vv[ct], wav[ct], p);
            }
            if (ok) {
                unsigned* qrow = q_bfu + (size_t)row * 64;
                #pragma unroll
                for (int tp = 0; tp < 4; ++tp) {
                    unsigned lo = bf16_rne(vv[2 * tp]);        // col tp*32+cidx
                    unsigned hi = bf16_rne(vv[2 * tp + 1]);    // col tp*32+16+cidx
                    qrow[tp * 16 + cidx] = lo | (hi << 16);
                }
            }
            p += __shfl_xor(p, 1, 64);
            p += __shfl_xor(p, 2, 64);
            p += __shfl_xor(p, 4, 64);
            p += __shfl_xor(p, 8, 64);
            if (ok && cidx == 0) as_[row] = p;
        }
    }
}

// ---------------- CSR build (once; receivers are hop-invariant) -------------
__global__ void hist_kern(const int* __restrict__ rcv, int* __restrict__ deg, int E) {
    int e = blockIdx.x * blockDim.x + threadIdx.x;
    if (e < E) atomicAdd(&deg[rcv[e]], 1);
}

// hierarchical exclusive scan, phase 1: 2048 elems/block, wave-shuffle scan.
__global__ __launch_bounds__(256) void scan1_kern(
    const int* __restrict__ deg, int* __restrict__ rowptr,
    int* __restrict__ bsum, int N)
{
    const int t = threadIdx.x;
    const int base = blockIdx.x * 2048 + t * 8;
    int v[8]; int s = 0;
    #pragma unroll
    for (int j = 0; j < 8; ++j) {
        v[j] = (base + j < N) ? deg[base + j] : 0;
        s += v[j];
    }
    const int lane = t & 63;
    const int wv = t >> 6;   // 0..3
    int incl = s;
    #pragma unroll
    for (int o = 1; o < 64; o <<= 1) {
        int x = __shfl_up(incl, o, 64);
        if (lane >= o) incl += x;
    }
    __shared__ int wsum[4];
    if (lane == 63) wsum[wv] = incl;
    __syncthreads();
    int woff = 0;
    #pragma unroll
    for (int w = 0; w < 4; ++w) woff += (w < wv) ? wsum[w] : 0;
    int excl = woff + incl - s;
    #pragma unroll
    for (int j = 0; j < 8; ++j) {
        if (base + j < N) rowptr[base + j] = excl;
        excl += v[j];
    }
    if (t == 255) bsum[blockIdx.x] = woff + incl;
}

// phase 2: single wave scans block sums (exclusive, in place); writes rowptr[N].
__global__ void scan2_kern(int* __restrict__ bsum, int* __restrict__ rowptr,
                           int nb, int N, int E)
{
    const int lane = threadIdx.x;   // 64 threads
    int carry = 0;
    for (int c = 0; c < nb; c += 64) {
        int i = c + lane;
        int v = (i < nb) ? bsum[i] : 0;
        int incl = v;
        #pragma unroll
        for (int o = 1; o < 64; o <<= 1) {
            int x = __shfl_up(incl, o, 64);
            if (lane >= o) incl += x;
        }
        if (i < nb) bsum[i] = carry + incl - v;
        carry += __shfl(incl, 63, 64);
    }
    if (lane == 0) rowptr[N] = E;
}

// phase 3: add block offsets; fill cursor copy.
__global__ void scan3_kern(int* __restrict__ rowptr, int* __restrict__ cursor,
                           const int* __restrict__ bsum, int N)
{
    int i = blockIdx.x * blockDim.x + threadIdx.x;
    if (i >= N) return;
    int v = rowptr[i] + bsum[i >> 11];
    rowptr[i] = v;
    cursor[i] = v;
}

__global__ void fill_kern(const int* __restrict__ snd, const int* __restrict__ rcv,
                          int* __restrict__ cursor, int* __restrict__ csr_snd, int E)
{
    int e = blockIdx.x * blockDim.x + threadIdx.x;
    if (e >= E) return;
    int pos = atomicAdd(&cursor[rcv[e]], 1);
    csr_snd[pos] = snd[e];
}

// ---------------- fused pull-based GAT node update --------------------------
// One wave per node. Softmax over as_[senders] (receiver terms cancel).
// deg<=64 path: csr/as_ gathered ONCE into registers; NO max-shift (logits
// are O(5) dots of unit-variance vectors — exp cannot overflow; weights are
// mathematically identical). Feature accumulate: 4 EDGES per trip,
// quarter-wave per edge, uint4 (16B) loads; cross-quarter shfl_xor reduce;
// float4 stores.
__global__ __launch_bounds__(256) void gat_node_kern(
    const unsigned* __restrict__ q_bfu, const float* __restrict__ as_,
    const int* __restrict__ rowptr, const int* __restrict__ csr_snd,
    float* __restrict__ xout, int N)
{
    const int lane = threadIdx.x & 63;
    const int n = blockIdx.x * 4 + (threadIdx.x >> 6);
    if (n >= N) return;
    const int start = rowptr[n], end = rowptr[n + 1];
    const int deg = end - start;

    if (deg <= 64) {
        const int i = start + lane;
        const bool valid = i < end;
        const int   s_c = valid ? csr_snd[i] : 0;
        const float e = valid ? __expf(as_[s_c]) : 0.f;
        float d = e;
        #pragma unroll
        for (int o = 1; o < 64; o <<= 1) d += __shfl_xor(d, o, 64);
        const float wgt = e * ((d > 0.f) ? (1.f / d) : 0.f);

        const int qw = lane >> 4;       // quarter-wave = edge slot 0..3
        const int ql = lane & 15;       // lane within quarter
        float4 accLo = make_float4(0.f, 0.f, 0.f, 0.f);
        float4 accHi = make_float4(0.f, 0.f, 0.f, 0.f);
        for (int kb = 0; kb < deg; kb += 4) {
            const int k = kb + qw;
            const int idx = (k < deg) ? k : (deg - 1);
            const int   s    = __shfl(s_c, idx, 64);
            float       coef = __shfl(wgt, idx, 64);
            if (k >= deg) coef = 0.f;
            const uint4 pv = *(const uint4*)(q_bfu + (size_t)s * 64 + 4 * ql);
            accLo.x = fmaf(coef, bf_lo(pv.x), accLo.x);
            accHi.x = fmaf(coef, bf_hi(pv.x), accHi.x);
            accLo.y = fmaf(coef, bf_lo(pv.y), accLo.y);
            accHi.y = fmaf(coef, bf_hi(pv.y), accHi.y);
            accLo.z = fmaf(coef, bf_lo(pv.z), accLo.z);
            accHi.z = fmaf(coef, bf_hi(pv.z), accHi.z);
            accLo.w = fmaf(coef, bf_lo(pv.w), accLo.w);
            accHi.w = fmaf(coef, bf_hi(pv.w), accHi.w);
        }
        // combine the 4 edge slots (lanes ^16, ^32)
        #pragma unroll
        for (int o = 16; o <= 32; o <<= 1) {
            accLo.x += __shfl_xor(accLo.x, o, 64);
            accLo.y += __shfl_xor(accLo.y, o, 64);
            accLo.z += __shfl_xor(accLo.z, o, 64);
            accLo.w += __shfl_xor(accLo.w, o, 64);
            accHi.x += __shfl_xor(accHi.x, o, 64);
            accHi.y += __shfl_xor(accHi.y, o, 64);
            accHi.z += __shfl_xor(accHi.z, o, 64);
            accHi.w += __shfl_xor(accHi.w, o, 64);
        }
        if (qw == 0) {
            // lane ql holds uints u=4*ql..4*ql+3: lo -> cols c0..c0+3, hi -> +16
            const int c0 = (ql >> 2) * 32 + (ql & 3) * 4;
            float4 lo4, hi4;
            lo4.x = accLo.x > 0.f ? accLo.x : 0.01f * accLo.x;
            lo4.y = accLo.y > 0.f ? accLo.y : 0.01f * accLo.y;
            lo4.z = accLo.z > 0.f ? accLo.z : 0.01f * accLo.z;
            lo4.w = accLo.w > 0.f ? accLo.w : 0.01f * accLo.w;
            hi4.x = accHi.x > 0.f ? accHi.x : 0.01f * accHi.x;
            hi4.y = accHi.y > 0.f ? accHi.y : 0.01f * accHi.y;
            hi4.z = accHi.z > 0.f ? accHi.z : 0.01f * accHi.z;
            hi4.w = accHi.w > 0.f ? accHi.w : 0.01f * accHi.w;
            *(float4*)(xout + (size_t)n * FD + c0)      = lo4;
            *(float4*)(xout + (size_t)n * FD + c0 + 16) = hi4;
        }
    } else {
        // general fallback (rare): 3-pass with max-shift, per-uint lanes
        float m = -3.4e38f;
        for (int i = start + lane; i < end; i += 64) m = fmaxf(m, as_[csr_snd[i]]);
        #pragma unroll
        for (int o = 1; o < 64; o <<= 1) m = fmaxf(m, __shfl_xor(m, o, 64));
        float d = 0.f;
        for (int i = start + lane; i < end; i += 64) d += __expf(as_[csr_snd[i]] - m);
        #pragma unroll
        for (int o = 1; o < 64; o <<= 1) d += __shfl_xor(d, o, 64);
        const float inv = (d > 0.f) ? (1.f / d) : 0.f;
        float accx = 0.f, accy = 0.f;
        for (int i = start; i < end; ++i) {
            const int s = csr_snd[i];
            const float coef = __expf(as_[s] - m) * inv;
            const unsigned pv = q_bfu[(size_t)s * 64 + lane];
            accx = fmaf(coef, bf_lo(pv), accx);
            accy = fmaf(coef, bf_hi(pv), accy);
        }
        accx = accx > 0.f ? accx : 0.01f * accx;
        accy = accy > 0.f ? accy : 0.01f * accy;
        const int c0 = (lane >> 4) * 32 + (lane & 15);
        xout[(size_t)n * FD + c0]      = accx;
        xout[(size_t)n * FD + c0 + 16] = accy;
    }
}

// agg[g] = sum of x rows with gidx==g (gidx sorted -> run-length accumulate)
__global__ __launch_bounds__(256) void agg_kern(
    const float* __restrict__ x, const int* __restrict__ gidx,
    float* __restrict__ agg, int N)
{
    const int c  = threadIdx.x & 127;
    const int rl = threadIdx.x >> 7;   // 0..1
    int n   = blockIdx.x * 128 + rl;
    int end = blockIdx.x * 128 + 128;
    if (end > N) end = N;
    float acc = 0.f; int curg = -1;
    for (; n < end; n += 2) {
        int g = gidx[n];
        if (g != curg) {
            if (curg >= 0) atomAddF(&agg[(size_t)curg * FD + c], acc);
            curg = g; acc = 0.f;
        }
        acc += x[(size_t)n * FD + c];
    }
    if (curg >= 0) atomAddF(&agg[(size_t)curg * FD + c], acc);
}

// g_out = concat([agg, globals]) @ Wg + bg.  One block per graph; 256 thr =
// 2 split-K halves x 128 output cols; Wg reads coalesced across cols.
__global__ __launch_bounds__(256) void glob_kern(
    const float* __restrict__ agg, const float* __restrict__ glb,
    const float* __restrict__ Wg, const float* __restrict__ bg,
    float* __restrict__ gout, int G)
{
    __shared__ float xv[256];
    __shared__ float part[128];
    const int g = blockIdx.x;
    const int t = threadIdx.x;
    if (t < 128) xv[t] = agg[(size_t)g * FD + t];
    else         xv[t] = glb[(size_t)g * FD + (t - 128)];
    __syncthreads();
    const int c = t & 127, half = t >> 7;
    const float* __restrict__ W = Wg + (size_t)half * FD * FD;
    const float* __restrict__ xh = xv + half * FD;
    float acc = 0.f;
    #pragma unroll 8
    for (int k = 0; k < FD; ++k)
        acc = fmaf(xh[k], W[(size_t)k * FD + c], acc);
    if (half == 1) part[c] = acc;
    __syncthreads();
    if (half == 0) gout[(size_t)g * FD + c] = acc + part[c] + bg[c];
}

extern "C" void kernel_launch(void* const* d_in, const int* in_sizes, int n_in,
                              void* d_out, int out_size, void* d_ws, size_t ws_size,
                              hipStream_t stream)
{
    const float* nodes    = (const float*)d_in[0];
    const float* globals_ = (const float*)d_in[1];
    const float* Wq       = (const float*)d_in[2];
    const float* bq       = (const float*)d_in[3];
    const float* Wa       = (const float*)d_in[4];
    const float* ba       = (const float*)d_in[5];  (void)ba;  // cancels in softmax
    const float* Wg       = (const float*)d_in[6];
    const float* bg       = (const float*)d_in[7];
    const int* senders    = (const int*)d_in[8];
    const int* receivers  = (const int*)d_in[9];
    const int* gidx       = (const int*)d_in[10];

    const int N    = in_sizes[0] / FD;
    const int G    = in_sizes[1] / FD;
    const int E    = in_sizes[8];
    const int HOPS = in_sizes[3] / FD;
    const int NB   = (N + 2047) / 2048;   // scan blocks

    // workspace layout
    float* ws = (float*)d_ws;
    size_t off = 0;
    unsigned* q_bfu = (unsigned*)ws;  off += (size_t)N * 64;   // packed bf16 q
    float* xbuf = ws + off;        off += (size_t)N * FD;
    float* agg  = ws + off;        off += (size_t)G * FD;
    float* as_  = ws + off;        off += N;
    int* deg     = (int*)(ws + off); off += N;
    int* rowptr  = (int*)(ws + off); off += N + 1;
    int* cursor  = (int*)(ws + off); off += N;
    int* bsum    = (int*)(ws + off); off += NB;
    int* csr_snd = (int*)(ws + off); off += E;
    off = (off + 3) & ~(size_t)3;                       // 16B-align for short8 loads
    unsigned short* wq_hi = (unsigned short*)(ws + off); off += (size_t)HOPS * 16384 / 2;
    unsigned short* wq_lo = (unsigned short*)(ws + off); off += (size_t)HOPS * 16384 / 2;

    float* xout_final = (float*)d_out;                  // N*FD
    float* gout = (float*)d_out + (size_t)N * FD;       // G*FD

    // ---- one-time prep: CSR (receivers identical across hops) + W bf16 frags
    hipMemsetAsync(deg, 0, (size_t)N * sizeof(int), stream);
    hipMemsetAsync(agg, 0, (size_t)G * FD * sizeof(float), stream);
    hist_kern<<<(E + 255) / 256, 256, 0, stream>>>(receivers, deg, E);
    scan1_kern<<<NB, 256, 0, stream>>>(deg, rowptr, bsum, N);
    scan2_kern<<<1, 64, 0, stream>>>(bsum, rowptr, NB, N, E);
    scan3_kern<<<(N + 255) / 256, 256, 0, stream>>>(rowptr, cursor, bsum, N);
    fill_kern<<<(E + 255) / 256, 256, 0, stream>>>(senders, receivers, cursor, csr_snd, E);
    const int wtot = HOPS * 2048;
    wprep_kern<<<(wtot + 255) / 256, 256, 0, stream>>>(Wq, wq_hi, wq_lo, wtot);

    const float* xin = nodes;
    for (int h = 0; h < HOPS; ++h) {
        float* xout = (h == HOPS - 1) ? xout_final : xbuf;
        const unsigned short* whi_h = wq_hi + (size_t)h * 16384;
        const unsigned short* wlo_h = wq_lo + (size_t)h * 16384;
        const float* bq_h = bq + (size_t)h * FD;
        const float* Wa_h = Wa + (size_t)h * 2 * FD;

        qkern_mfma<<<(N + 127) / 128, 256, 0, stream>>>(xin, whi_h, wlo_h, bq_h,
                                                        Wa_h, q_bfu, as_, N);
        gat_node_kern<<<(N + 3) / 4, 256, 0, stream>>>(q_bfu, as_, rowptr, csr_snd,
                                                       xout, N);
        xin = xout;
    }

    agg_kern<<<(N + 127) / 128, 256, 0, stream>>>(xin, gidx, agg, N);
    glob_kern<<<G, 256, 0, stream>>>(agg, globals_, Wg, bg, gout, G);
}

// Round 13
// 206.787 us; speedup vs baseline: 1.0897x; 1.0416x over previous
//
#include <hip/hip_runtime.h>
#include <hip/hip_bf16.h>
#include <cstddef>

#define FD 128   // feature dim D == H == 128

typedef __attribute__((ext_vector_type(8))) short short8v;   // 8 bf16 (4 VGPRs)
typedef __attribute__((ext_vector_type(4))) float f32x4;

__device__ __forceinline__ void atomAddF(float* p, float v) {
    unsafeAtomicAdd(p, v);   // HW global_atomic_add_f32 on gfx950
}

__device__ __forceinline__ unsigned short bf16_rne(float x) {
    unsigned u = __float_as_uint(x);
    return (unsigned short)((u + 0x7fffu + ((u >> 16) & 1u)) >> 16);
}

__device__ __forceinline__ float bf_lo(unsigned u) { return __uint_as_float(u << 16); }
__device__ __forceinline__ float bf_hi(unsigned u) { return __uint_as_float(u & 0xffff0000u); }

// ---- one-time W prep: Wq (fp32 [hop][k][col]) -> B-fragment-ordered bf16
// hi/lo.  Fragment order: [hop][kk(4)][ct(8)][lane(64)][j(8)], where the
// element is W[kk*32 + (lane>>4)*8 + j][ct*16 + (lane&15)].
__global__ void wprep_kern(const float* __restrict__ Wq,
                           unsigned short* __restrict__ whi,
                           unsigned short* __restrict__ wlo, int total)
{
    int t = blockIdx.x * blockDim.x + threadIdx.x;
    if (t >= total) return;                 // total = HOPS*2048
    const int hop = t >> 11;
    const int kk  = (t >> 9) & 3;
    const int ct  = (t >> 6) & 7;
    const int l   = t & 63;
    const float* Wh = Wq + (size_t)hop * FD * FD;
    #pragma unroll
    for (int j = 0; j < 8; ++j) {
        float w = Wh[(size_t)(kk * 32 + (l >> 4) * 8 + j) * FD + ct * 16 + (l & 15)];
        unsigned short h = bf16_rne(w);
        float hf = __uint_as_float((unsigned)h << 16);
        whi[(size_t)t * 8 + j] = h;
        wlo[(size_t)t * 8 + j] = bf16_rne(w - hf);
    }
}

// ---- q = xin @ Wq[h] + bq[h] via bf16 MFMA.  A = bf16(x) single fragment.
// B hi/lo split for fp32-grade weights.  W fragments LDS-STAGED once per
// block (64KB > 32KB L1, so un-staged every wave re-streams W from L2);
// 4 waves then read via conflict-free ds_read_b128.  W-reuse: each wave
// computes 32 rows (two 16-row A strips) per B pair.
// Fused sender-logit as_ = q . Wa[:128]  (receiver term cancels in softmax).
// q emitted bf16-PACKED: q_bfu[row][u] holds cols c0=(u>>4)*32+(u&15) (lo),
// c0+16 (hi).
// Block: 256 thr = 4 waves; 128 rows/block; LDS 64KB -> 2 blocks/CU.
__global__ __launch_bounds__(256) void qkern_mfma(
    const float* __restrict__ xin,
    const unsigned short* __restrict__ whi, const unsigned short* __restrict__ wlo,
    const float* __restrict__ bq, const float* __restrict__ Wa,
    unsigned* __restrict__ q_bfu, float* __restrict__ as_, int N)
{
    __shared__ unsigned short lds_hi[16384];   // 32KB
    __shared__ unsigned short lds_lo[16384];   // 32KB

    const int t    = threadIdx.x;
    const int lane = t & 63;
    const int w    = t >> 6;                    // wave 0..3
    const int rowBase = blockIdx.x * 128 + w * 32;

    // cooperative stage: 8192 uint4 per table / 256 thr = 32 trips each
    {
        const uint4* src_hi = (const uint4*)whi;
        const uint4* src_lo = (const uint4*)wlo;
        uint4* dst_hi = (uint4*)lds_hi;
        uint4* dst_lo = (uint4*)lds_lo;
        #pragma unroll
        for (int i = 0; i < 8; ++i) {
            dst_hi[t + i * 256] = src_hi[t + i * 256];
            dst_lo[t + i * 256] = src_lo[t + i * 256];
        }
    }
    __syncthreads();
    if (rowBase >= N) return;

    const int kgrp = lane >> 4;                 // 0..3
    const int cidx = lane & 15;

    // A-rows for the two strips (clamped; OOB rows guarded at store)
    int arow0 = rowBase + cidx;       if (arow0 >= N) arow0 = N - 1;
    int arow1 = rowBase + 16 + cidx;  if (arow1 >= N) arow1 = N - 1;
    const float* __restrict__ xr0 = xin + (size_t)arow0 * FD;
    const float* __restrict__ xr1 = xin + (size_t)arow1 * FD;

    f32x4 acc0[8], acc1[8];
    #pragma unroll
    for (int ct = 0; ct < 8; ++ct) {
        acc0[ct] = (f32x4){0.f, 0.f, 0.f, 0.f};
        acc1[ct] = (f32x4){0.f, 0.f, 0.f, 0.f};
    }

    #pragma unroll
    for (int kk = 0; kk < 4; ++kk) {
        const int ko = kk * 32 + kgrp * 8;
        float4 x0a = *(const float4*)(xr0 + ko);
        float4 x0b = *(const float4*)(xr0 + ko + 4);
        float4 x1a = *(const float4*)(xr1 + ko);
        float4 x1b = *(const float4*)(xr1 + ko + 4);
        float v0[8] = {x0a.x, x0a.y, x0a.z, x0a.w, x0b.x, x0b.y, x0b.z, x0b.w};
        float v1[8] = {x1a.x, x1a.y, x1a.z, x1a.w, x1b.x, x1b.y, x1b.z, x1b.w};
        short8v a0, a1;
        #pragma unroll
        for (int j = 0; j < 8; ++j) {
            a0[j] = (short)bf16_rne(v0[j]);
            a1[j] = (short)bf16_rne(v1[j]);
        }
        #pragma unroll
        for (int ct = 0; ct < 8; ++ct) {
            const int fo = ((kk * 8 + ct) * 64 + lane) * 8;
            short8v bhi = *(const short8v*)(lds_hi + fo);
            short8v blo = *(const short8v*)(lds_lo + fo);
            acc0[ct] = __builtin_amdgcn_mfma_f32_16x16x32_bf16(a0, bhi, acc0[ct], 0, 0, 0);
            acc0[ct] = __builtin_amdgcn_mfma_f32_16x16x32_bf16(a0, blo, acc0[ct], 0, 0, 0);
            acc1[ct] = __builtin_amdgcn_mfma_f32_16x16x32_bf16(a1, bhi, acc1[ct], 0, 0, 0);
            acc1[ct] = __builtin_amdgcn_mfma_f32_16x16x32_bf16(a1, blo, acc1[ct], 0, 0, 0);
        }
    }

    // epilogue: bias, packed-bf16 q store, fused as_ dot — per row strip
    float bqv[8], wav[8];
    #pragma unroll
    for (int ct = 0; ct < 8; ++ct) {
        bqv[ct] = bq[ct * 16 + cidx];
        wav[ct] = Wa[ct * 16 + cidx];
    }
    #pragma unroll
    for (int strip = 0; strip < 2; ++strip) {
        const f32x4* acc = strip ? acc1 : acc0;
        const int sbase = rowBase + strip * 16;
        #pragma unroll
        for (int j = 0; j < 4; ++j) {
            const int row = sbase + kgrp * 4 + j;    // C/D: row=(lane>>4)*4+reg
            const bool ok = row < N;
            float p = 0.f;
            float vv[8];
            #pragma unroll
            for (int ct = 0; ct < 8; ++ct) {
                vv[ct] = acc[ct][j] + bqv[ct];
                p = fmaf(vv[ct], wav[ct], p);
            }
            if (ok) {
                unsigned* qrow = q_bfu + (size_t)row * 64;
                #pragma unroll
                for (int tp = 0; tp < 4; ++tp) {
                    unsigned lo = bf16_rne(vv[2 * tp]);        // col tp*32+cidx
                    unsigned hi = bf16_rne(vv[2 * tp + 1]);    // col tp*32+16+cidx
                    qrow[tp * 16 + cidx] = lo | (hi << 16);
                }
            }
            p += __shfl_xor(p, 1, 64);
            p += __shfl_xor(p, 2, 64);
            p += __shfl_xor(p, 4, 64);
            p += __shfl_xor(p, 8, 64);
            if (ok && cidx == 0) as_[row] = p;
        }
    }
}

// ---------------- CSR build (once; receivers are hop-invariant) -------------
__global__ void hist_kern(const int* __restrict__ rcv, int* __restrict__ deg, int E) {
    int e = blockIdx.x * blockDim.x + threadIdx.x;
    if (e < E) atomicAdd(&deg[rcv[e]], 1);
}

// hierarchical exclusive scan, phase 1: 2048 elems/block, wave-shuffle scan.
__global__ __launch_bounds__(256) void scan1_kern(
    const int* __restrict__ deg, int* __restrict__ rowptr,
    int* __restrict__ bsum, int N)
{
    const int t = threadIdx.x;
    const int base = blockIdx.x * 2048 + t * 8;
    int v[8]; int s = 0;
    #pragma unroll
    for (int j = 0; j < 8; ++j) {
        v[j] = (base + j < N) ? deg[base + j] : 0;
        s += v[j];
    }
    const int lane = t & 63;
    const int wv = t >> 6;   // 0..3
    int incl = s;
    #pragma unroll
    for (int o = 1; o < 64; o <<= 1) {
        int x = __shfl_up(incl, o, 64);
        if (lane >= o) incl += x;
    }
    __shared__ int wsum[4];
    if (lane == 63) wsum[wv] = incl;
    __syncthreads();
    int woff = 0;
    #pragma unroll
    for (int w = 0; w < 4; ++w) woff += (w < wv) ? wsum[w] : 0;
    int excl = woff + incl - s;
    #pragma unroll
    for (int j = 0; j < 8; ++j) {
        if (base + j < N) rowptr[base + j] = excl;
        excl += v[j];
    }
    if (t == 255) bsum[blockIdx.x] = woff + incl;
}

// phase 2: single wave scans block sums (exclusive, in place); writes rowptr[N].
__global__ void scan2_kern(int* __restrict__ bsum, int* __restrict__ rowptr,
                           int nb, int N, int E)
{
    const int lane = threadIdx.x;   // 64 threads
    int carry = 0;
    for (int c = 0; c < nb; c += 64) {
        int i = c + lane;
        int v = (i < nb) ? bsum[i] : 0;
        int incl = v;
        #pragma unroll
        for (int o = 1; o < 64; o <<= 1) {
            int x = __shfl_up(incl, o, 64);
            if (lane >= o) incl += x;
        }
        if (i < nb) bsum[i] = carry + incl - v;
        carry += __shfl(incl, 63, 64);
    }
    if (lane == 0) rowptr[N] = E;
}

// phase 3: add block offsets; fill cursor copy.
__global__ void scan3_kern(int* __restrict__ rowptr, int* __restrict__ cursor,
                           const int* __restrict__ bsum, int N)
{
    int i = blockIdx.x * blockDim.x + threadIdx.x;
    if (i >= N) return;
    int v = rowptr[i] + bsum[i >> 11];
    rowptr[i] = v;
    cursor[i] = v;
}

__global__ void fill_kern(const int* __restrict__ snd, const int* __restrict__ rcv,
                          int* __restrict__ cursor, int* __restrict__ csr_snd, int E)
{
    int e = blockIdx.x * blockDim.x + threadIdx.x;
    if (e >= E) return;
    int pos = atomicAdd(&cursor[rcv[e]], 1);
    csr_snd[pos] = snd[e];
}

// ---------------- fused pull-based GAT node update --------------------------
// One wave per node. Softmax over as_[senders] (receiver terms cancel).
// deg<=64 path: csr/as_ gathered ONCE into registers; NO max-shift (logits
// are O(5) dots of unit-variance vectors — exp cannot overflow; weights are
// mathematically identical). Feature accumulate: 4 EDGES per trip,
// quarter-wave per edge, uint4 (16B) loads; cross-quarter shfl_xor reduce;
// float4 stores.
__global__ __launch_bounds__(256) void gat_node_kern(
    const unsigned* __restrict__ q_bfu, const float* __restrict__ as_,
    const int* __restrict__ rowptr, const int* __restrict__ csr_snd,
    float* __restrict__ xout, int N)
{
    const int lane = threadIdx.x & 63;
    const int n = blockIdx.x * 4 + (threadIdx.x >> 6);
    if (n >= N) return;
    const int start = rowptr[n], end = rowptr[n + 1];
    const int deg = end - start;

    if (deg <= 64) {
        const int i = start + lane;
        const bool valid = i < end;
        const int   s_c = valid ? csr_snd[i] : 0;
        const float e = valid ? __expf(as_[s_c]) : 0.f;
        float d = e;
        #pragma unroll
        for (int o = 1; o < 64; o <<= 1) d += __shfl_xor(d, o, 64);
        const float wgt = e * ((d > 0.f) ? (1.f / d) : 0.f);

        const int qw = lane >> 4;       // quarter-wave = edge slot 0..3
        const int ql = lane & 15;       // lane within quarter
        float4 accLo = make_float4(0.f, 0.f, 0.f, 0.f);
        float4 accHi = make_float4(0.f, 0.f, 0.f, 0.f);
        for (int kb = 0; kb < deg; kb += 4) {
            const int k = kb + qw;
            const int idx = (k < deg) ? k : (deg - 1);
            const int   s    = __shfl(s_c, idx, 64);
            float       coef = __shfl(wgt, idx, 64);
            if (k >= deg) coef = 0.f;
            const uint4 pv = *(const uint4*)(q_bfu + (size_t)s * 64 + 4 * ql);
            accLo.x = fmaf(coef, bf_lo(pv.x), accLo.x);
            accHi.x = fmaf(coef, bf_hi(pv.x), accHi.x);
            accLo.y = fmaf(coef, bf_lo(pv.y), accLo.y);
            accHi.y = fmaf(coef, bf_hi(pv.y), accHi.y);
            accLo.z = fmaf(coef, bf_lo(pv.z), accLo.z);
            accHi.z = fmaf(coef, bf_hi(pv.z), accHi.z);
            accLo.w = fmaf(coef, bf_lo(pv.w), accLo.w);
            accHi.w = fmaf(coef, bf_hi(pv.w), accHi.w);
        }
        // combine the 4 edge slots (lanes ^16, ^32)
        #pragma unroll
        for (int o = 16; o <= 32; o <<= 1) {
            accLo.x += __shfl_xor(accLo.x, o, 64);
            accLo.y += __shfl_xor(accLo.y, o, 64);
            accLo.z += __shfl_xor(accLo.z, o, 64);
            accLo.w += __shfl_xor(accLo.w, o, 64);
            accHi.x += __shfl_xor(accHi.x, o, 64);
            accHi.y += __shfl_xor(accHi.y, o, 64);
            accHi.z += __shfl_xor(accHi.z, o, 64);
            accHi.w += __shfl_xor(accHi.w, o, 64);
        }
        if (qw == 0) {
            // lane ql holds uints u=4*ql..4*ql+3: lo -> cols c0..c0+3, hi -> +16
            const int c0 = (ql >> 2) * 32 + (ql & 3) * 4;
            float4 lo4, hi4;
            lo4.x = accLo.x > 0.f ? accLo.x : 0.01f * accLo.x;
            lo4.y = accLo.y > 0.f ? accLo.y : 0.01f * accLo.y;
            lo4.z = accLo.z > 0.f ? accLo.z : 0.01f * accLo.z;
            lo4.w = accLo.w > 0.f ? accLo.w : 0.01f * accLo.w;
            hi4.x = accHi.x > 0.f ? accHi.x : 0.01f * accHi.x;
            hi4.y = accHi.y > 0.f ? accHi.y : 0.01f * accHi.y;
            hi4.z = accHi.z > 0.f ? accHi.z : 0.01f * accHi.z;
            hi4.w = accHi.w > 0.f ? accHi.w : 0.01f * accHi.w;
            *(float4*)(xout + (size_t)n * FD + c0)      = lo4;
            *(float4*)(xout + (size_t)n * FD + c0 + 16) = hi4;
        }
    } else {
        // general fallback (rare): 3-pass with max-shift, per-uint lanes
        float m = -3.4e38f;
        for (int i = start + lane; i < end; i += 64) m = fmaxf(m, as_[csr_snd[i]]);
        #pragma unroll
        for (int o = 1; o < 64; o <<= 1) m = fmaxf(m, __shfl_xor(m, o, 64));
        float d = 0.f;
        for (int i = start + lane; i < end; i += 64) d += __expf(as_[csr_snd[i]] - m);
        #pragma unroll
        for (int o = 1; o < 64; o <<= 1) d += __shfl_xor(d, o, 64);
        const float inv = (d > 0.f) ? (1.f / d) : 0.f;
        float accx = 0.f, accy = 0.f;
        for (int i = start; i < end; ++i) {
            const int s = csr_snd[i];
            const float coef = __expf(as_[s] - m) * inv;
            const unsigned pv = q_bfu[(size_t)s * 64 + lane];
            accx = fmaf(coef, bf_lo(pv), accx);
            accy = fmaf(coef, bf_hi(pv), accy);
        }
        accx = accx > 0.f ? accx : 0.01f * accx;
        accy = accy > 0.f ? accy : 0.01f * accy;
        const int c0 = (lane >> 4) * 32 + (lane & 15);
        xout[(size_t)n * FD + c0]      = accx;
        xout[(size_t)n * FD + c0 + 16] = accy;
    }
}

// agg[g] = sum of x rows with gidx==g (gidx sorted -> run-length accumulate)
__global__ __launch_bounds__(256) void agg_kern(
    const float* __restrict__ x, const int* __restrict__ gidx,
    float* __restrict__ agg, int N)
{
    const int c  = threadIdx.x & 127;
    const int rl = threadIdx.x >> 7;   // 0..1
    int n   = blockIdx.x * 128 + rl;
    int end = blockIdx.x * 128 + 128;
    if (end > N) end = N;
    float acc = 0.f; int curg = -1;
    for (; n < end; n += 2) {
        int g = gidx[n];
        if (g != curg) {
            if (curg >= 0) atomAddF(&agg[(size_t)curg * FD + c], acc);
            curg = g; acc = 0.f;
        }
        acc += x[(size_t)n * FD + c];
    }
    if (curg >= 0) atomAddF(&agg[(size_t)curg * FD + c], acc);
}

// g_out = concat([agg, globals]) @ Wg + bg.  One block per graph; 256 thr =
// 2 split-K halves x 128 output cols; Wg reads coalesced across cols.
__global__ __launch_bounds__(256) void glob_kern(
    const float* __restrict__ agg, const float* __restrict__ glb,
    const float* __restrict__ Wg, const float* __restrict__ bg,
    float* __restrict__ gout, int G)
{
    __shared__ float xv[256];
    __shared__ float part[128];
    const int g = blockIdx.x;
    const int t = threadIdx.x;
    if (t < 128) xv[t] = agg[(size_t)g * FD + t];
    else         xv[t] = glb[(size_t)g * FD + (t - 128)];
    __syncthreads();
    const int c = t & 127, half = t >> 7;
    const float* __restrict__ W = Wg + (size_t)half * FD * FD;
    const float* __restrict__ xh = xv + half * FD;
    float acc = 0.f;
    #pragma unroll 8
    for (int k = 0; k < FD; ++k)
        acc = fmaf(xh[k], W[(size_t)k * FD + c], acc);
    if (half == 1) part[c] = acc;
    __syncthreads();
    if (half == 0) gout[(size_t)g * FD + c] = acc + part[c] + bg[c];
}

extern "C" void kernel_launch(void* const* d_in, const int* in_sizes, int n_in,
                              void* d_out, int out_size, void* d_ws, size_t ws_size,
                              hipStream_t stream)
{
    const float* nodes    = (const float*)d_in[0];
    const float* globals_ = (const float*)d_in[1];
    const float* Wq       = (const float*)d_in[2];
    const float* bq       = (const float*)d_in[3];
    const float* Wa       = (const float*)d_in[4];
    const float* ba       = (const float*)d_in[5];  (void)ba;  // cancels in softmax
    const float* Wg       = (const float*)d_in[6];
    const float* bg       = (const float*)d_in[7];
    const int* senders    = (const int*)d_in[8];
    const int* receivers  = (const int*)d_in[9];
    const int* gidx       = (const int*)d_in[10];

    const int N    = in_sizes[0] / FD;
    const int G    = in_sizes[1] / FD;
    const int E    = in_sizes[8];
    const int HOPS = in_sizes[3] / FD;
    const int NB   = (N + 2047) / 2048;   // scan blocks

    // workspace layout
    float* ws = (float*)d_ws;
    size_t off = 0;
    unsigned* q_bfu = (unsigned*)ws;  off += (size_t)N * 64;   // packed bf16 q
    float* xbuf = ws + off;        off += (size_t)N * FD;
    float* agg  = ws + off;        off += (size_t)G * FD;
    float* as_  = ws + off;        off += N;
    int* deg     = (int*)(ws + off); off += N;
    int* rowptr  = (int*)(ws + off); off += N + 1;
    int* cursor  = (int*)(ws + off); off += N;
    int* bsum    = (int*)(ws + off); off += NB;
    int* csr_snd = (int*)(ws + off); off += E;
    off = (off + 3) & ~(size_t)3;                       // 16B-align for short8 loads
    unsigned short* wq_hi = (unsigned short*)(ws + off); off += (size_t)HOPS * 16384 / 2;
    unsigned short* wq_lo = (unsigned short*)(ws + off); off += (size_t)HOPS * 16384 / 2;

    float* xout_final = (float*)d_out;                  // N*FD
    float* gout = (float*)d_out + (size_t)N * FD;       // G*FD

    // ---- one-time prep: CSR (receivers identical across hops) + W bf16 frags
    hipMemsetAsync(deg, 0, (size_t)N * sizeof(int), stream);
    hipMemsetAsync(agg, 0, (size_t)G * FD * sizeof(float), stream);
    hist_kern<<<(E + 255) / 256, 256, 0, stream>>>(receivers, deg, E);
    scan1_kern<<<NB, 256, 0, stream>>>(deg, rowptr, bsum, N);
    scan2_kern<<<1, 64, 0, stream>>>(bsum, rowptr, NB, N, E);
    scan3_kern<<<(N + 255) / 256, 256, 0, stream>>>(rowptr, cursor, bsum, N);
    fill_kern<<<(E + 255) / 256, 256, 0, stream>>>(senders, receivers, cursor, csr_snd, E);
    const int wtot = HOPS * 2048;
    wprep_kern<<<(wtot + 255) / 256, 256, 0, stream>>>(Wq, wq_hi, wq_lo, wtot);

    const float* xin = nodes;
    for (int h = 0; h < HOPS; ++h) {
        float* xout = (h == HOPS - 1) ? xout_final : xbuf;
        const unsigned short* whi_h = wq_hi + (size_t)h * 16384;
        const unsigned short* wlo_h = wq_lo + (size_t)h * 16384;
        const float* bq_h = bq + (size_t)h * FD;
        const float* Wa_h = Wa + (size_t)h * 2 * FD;

        qkern_mfma<<<(N + 127) / 128, 256, 0, stream>>>(xin, whi_h, wlo_h, bq_h,
                                                        Wa_h, q_bfu, as_, N);
        gat_node_kern<<<(N + 3) / 4, 256, 0, stream>>>(q_bfu, as_, rowptr, csr_snd,
                                                       xout, N);
        xin = xout;
    }

    agg_kern<<<(N + 127) / 128, 256, 0, stream>>>(xin, gidx, agg, N);
    glob_kern<<<G, 256, 0, stream>>>(agg, globals_, Wg, bg, gout, G);
}

// Round 14
// 204.471 us; speedup vs baseline: 1.1020x; 1.0113x over previous
//
#include <hip/hip_runtime.h>
#include <hip/hip_bf16.h>
#include <cstddef>

#define FD 128   // feature dim D == H == 128

typedef __attribute__((ext_vector_type(8))) short short8v;   // 8 bf16 (4 VGPRs)
typedef __attribute__((ext_vector_type(4))) float f32x4;

__device__ __forceinline__ void atomAddF(float* p, float v) {
    unsafeAtomicAdd(p, v);   // HW global_atomic_add_f32 on gfx950
}

__device__ __forceinline__ unsigned short bf16_rne(float x) {
    unsigned u = __float_as_uint(x);
    return (unsigned short)((u + 0x7fffu + ((u >> 16) & 1u)) >> 16);
}

__device__ __forceinline__ float bf_lo(unsigned u) { return __uint_as_float(u << 16); }
__device__ __forceinline__ float bf_hi(unsigned u) { return __uint_as_float(u & 0xffff0000u); }

// ---- one-time W prep: Wq (fp32 [hop][k][col]) -> B-fragment-ordered bf16
// hi/lo.  Fragment order: [hop][kk(4)][ct(8)][lane(64)][j(8)], where the
// element is W[kk*32 + (lane>>4)*8 + j][ct*16 + (lane&15)].
__global__ void wprep_kern(const float* __restrict__ Wq,
                           unsigned short* __restrict__ whi,
                           unsigned short* __restrict__ wlo, int total)
{
    int t = blockIdx.x * blockDim.x + threadIdx.x;
    if (t >= total) return;                 // total = HOPS*2048
    const int hop = t >> 11;
    const int kk  = (t >> 9) & 3;
    const int ct  = (t >> 6) & 7;
    const int l   = t & 63;
    const float* Wh = Wq + (size_t)hop * FD * FD;
    #pragma unroll
    for (int j = 0; j < 8; ++j) {
        float w = Wh[(size_t)(kk * 32 + (l >> 4) * 8 + j) * FD + ct * 16 + (l & 15)];
        unsigned short h = bf16_rne(w);
        float hf = __uint_as_float((unsigned)h << 16);
        whi[(size_t)t * 8 + j] = h;
        wlo[(size_t)t * 8 + j] = bf16_rne(w - hf);
    }
}

// ---- q = xin @ Wq[h] + bq[h] via bf16 MFMA.  A = bf16(x) single fragment.
// B hi/lo split for fp32-grade weights.  W fragments LDS-STAGED once per
// block; W-reuse: each wave computes 32 rows (two 16-row A strips) per B pair.
// Fused sender-logit as_ = q . Wa[:128]  (receiver term cancels in softmax).
// q emitted bf16-PACKED: q_bfu[row][u] holds cols c0=(u>>4)*32+(u&15) (lo),
// c0+16 (hi).
// Block: 256 thr = 4 waves; 128 rows/block; LDS 64KB -> 2 blocks/CU.
__global__ __launch_bounds__(256) void qkern_mfma(
    const float* __restrict__ xin,
    const unsigned short* __restrict__ whi, const unsigned short* __restrict__ wlo,
    const float* __restrict__ bq, const float* __restrict__ Wa,
    unsigned* __restrict__ q_bfu, float* __restrict__ as_, int N)
{
    __shared__ unsigned short lds_hi[16384];   // 32KB
    __shared__ unsigned short lds_lo[16384];   // 32KB

    const int t    = threadIdx.x;
    const int lane = t & 63;
    const int w    = t >> 6;                    // wave 0..3
    const int rowBase = blockIdx.x * 128 + w * 32;

    // cooperative stage: 8192 uint4 per table / 256 thr = 32 trips each
    {
        const uint4* src_hi = (const uint4*)whi;
        const uint4* src_lo = (const uint4*)wlo;
        uint4* dst_hi = (uint4*)lds_hi;
        uint4* dst_lo = (uint4*)lds_lo;
        #pragma unroll
        for (int i = 0; i < 8; ++i) {
            dst_hi[t + i * 256] = src_hi[t + i * 256];
            dst_lo[t + i * 256] = src_lo[t + i * 256];
        }
    }
    __syncthreads();
    if (rowBase >= N) return;

    const int kgrp = lane >> 4;                 // 0..3
    const int cidx = lane & 15;

    // A-rows for the two strips (clamped; OOB rows guarded at store)
    int arow0 = rowBase + cidx;       if (arow0 >= N) arow0 = N - 1;
    int arow1 = rowBase + 16 + cidx;  if (arow1 >= N) arow1 = N - 1;
    const float* __restrict__ xr0 = xin + (size_t)arow0 * FD;
    const float* __restrict__ xr1 = xin + (size_t)arow1 * FD;

    f32x4 acc0[8], acc1[8];
    #pragma unroll
    for (int ct = 0; ct < 8; ++ct) {
        acc0[ct] = (f32x4){0.f, 0.f, 0.f, 0.f};
        acc1[ct] = (f32x4){0.f, 0.f, 0.f, 0.f};
    }

    #pragma unroll
    for (int kk = 0; kk < 4; ++kk) {
        const int ko = kk * 32 + kgrp * 8;
        float4 x0a = *(const float4*)(xr0 + ko);
        float4 x0b = *(const float4*)(xr0 + ko + 4);
        float4 x1a = *(const float4*)(xr1 + ko);
        float4 x1b = *(const float4*)(xr1 + ko + 4);
        float v0[8] = {x0a.x, x0a.y, x0a.z, x0a.w, x0b.x, x0b.y, x0b.z, x0b.w};
        float v1[8] = {x1a.x, x1a.y, x1a.z, x1a.w, x1b.x, x1b.y, x1b.z, x1b.w};
        short8v a0, a1;
        #pragma unroll
        for (int j = 0; j < 8; ++j) {
            a0[j] = (short)bf16_rne(v0[j]);
            a1[j] = (short)bf16_rne(v1[j]);
        }
        #pragma unroll
        for (int ct = 0; ct < 8; ++ct) {
            const int fo = ((kk * 8 + ct) * 64 + lane) * 8;
            short8v bhi = *(const short8v*)(lds_hi + fo);
            short8v blo = *(const short8v*)(lds_lo + fo);
            acc0[ct] = __builtin_amdgcn_mfma_f32_16x16x32_bf16(a0, bhi, acc0[ct], 0, 0, 0);
            acc0[ct] = __builtin_amdgcn_mfma_f32_16x16x32_bf16(a0, blo, acc0[ct], 0, 0, 0);
            acc1[ct] = __builtin_amdgcn_mfma_f32_16x16x32_bf16(a1, bhi, acc1[ct], 0, 0, 0);
            acc1[ct] = __builtin_amdgcn_mfma_f32_16x16x32_bf16(a1, blo, acc1[ct], 0, 0, 0);
        }
    }

    // epilogue: bias, packed-bf16 q store, fused as_ dot — per row strip
    float bqv[8], wav[8];
    #pragma unroll
    for (int ct = 0; ct < 8; ++ct) {
        bqv[ct] = bq[ct * 16 + cidx];
        wav[ct] = Wa[ct * 16 + cidx];
    }
    #pragma unroll
    for (int strip = 0; strip < 2; ++strip) {
        const f32x4* acc = strip ? acc1 : acc0;
        const int sbase = rowBase + strip * 16;
        #pragma unroll
        for (int j = 0; j < 4; ++j) {
            const int row = sbase + kgrp * 4 + j;    // C/D: row=(lane>>4)*4+reg
            const bool ok = row < N;
            float p = 0.f;
            float vv[8];
            #pragma unroll
            for (int ct = 0; ct < 8; ++ct) {
                vv[ct] = acc[ct][j] + bqv[ct];
                p = fmaf(vv[ct], wav[ct], p);
            }
            if (ok) {
                unsigned* qrow = q_bfu + (size_t)row * 64;
                #pragma unroll
                for (int tp = 0; tp < 4; ++tp) {
                    unsigned lo = bf16_rne(vv[2 * tp]);        // col tp*32+cidx
                    unsigned hi = bf16_rne(vv[2 * tp + 1]);    // col tp*32+16+cidx
                    qrow[tp * 16 + cidx] = lo | (hi << 16);
                }
            }
            p += __shfl_xor(p, 1, 64);
            p += __shfl_xor(p, 2, 64);
            p += __shfl_xor(p, 4, 64);
            p += __shfl_xor(p, 8, 64);
            if (ok && cidx == 0) as_[row] = p;
        }
    }
}

// ---------------- CSR build (once; receivers are hop-invariant) -------------
__global__ void hist_kern(const int* __restrict__ rcv, int* __restrict__ deg, int E) {
    int e = blockIdx.x * blockDim.x + threadIdx.x;
    if (e < E) atomicAdd(&deg[rcv[e]], 1);
}

// hierarchical exclusive scan, phase 1: 2048 elems/block, wave-shuffle scan.
__global__ __launch_bounds__(256) void scan1_kern(
    const int* __restrict__ deg, int* __restrict__ rowptr,
    int* __restrict__ bsum, int N)
{
    const int t = threadIdx.x;
    const int base = blockIdx.x * 2048 + t * 8;
    int v[8]; int s = 0;
    #pragma unroll
    for (int j = 0; j < 8; ++j) {
        v[j] = (base + j < N) ? deg[base + j] : 0;
        s += v[j];
    }
    const int lane = t & 63;
    const int wv = t >> 6;   // 0..3
    int incl = s;
    #pragma unroll
    for (int o = 1; o < 64; o <<= 1) {
        int x = __shfl_up(incl, o, 64);
        if (lane >= o) incl += x;
    }
    __shared__ int wsum[4];
    if (lane == 63) wsum[wv] = incl;
    __syncthreads();
    int woff = 0;
    #pragma unroll
    for (int w = 0; w < 4; ++w) woff += (w < wv) ? wsum[w] : 0;
    int excl = woff + incl - s;
    #pragma unroll
    for (int j = 0; j < 8; ++j) {
        if (base + j < N) rowptr[base + j] = excl;
        excl += v[j];
    }
    if (t == 255) bsum[blockIdx.x] = woff + incl;
}

// phase 2: single wave scans block sums (exclusive, in place); writes rowptr[N].
__global__ void scan2_kern(int* __restrict__ bsum, int* __restrict__ rowptr,
                           int nb, int N, int E)
{
    const int lane = threadIdx.x;   // 64 threads
    int carry = 0;
    for (int c = 0; c < nb; c += 64) {
        int i = c + lane;
        int v = (i < nb) ? bsum[i] : 0;
        int incl = v;
        #pragma unroll
        for (int o = 1; o < 64; o <<= 1) {
            int x = __shfl_up(incl, o, 64);
            if (lane >= o) incl += x;
        }
        if (i < nb) bsum[i] = carry + incl - v;
        carry += __shfl(incl, 63, 64);
    }
    if (lane == 0) rowptr[N] = E;
}

// phase 3: add block offsets; fill cursor copy.
__global__ void scan3_kern(int* __restrict__ rowptr, int* __restrict__ cursor,
                           const int* __restrict__ bsum, int N)
{
    int i = blockIdx.x * blockDim.x + threadIdx.x;
    if (i >= N) return;
    int v = rowptr[i] + bsum[i >> 11];
    rowptr[i] = v;
    cursor[i] = v;
}

__global__ void fill_kern(const int* __restrict__ snd, const int* __restrict__ rcv,
                          int* __restrict__ cursor, int* __restrict__ csr_snd, int E)
{
    int e = blockIdx.x * blockDim.x + threadIdx.x;
    if (e >= E) return;
    int pos = atomicAdd(&cursor[rcv[e]], 1);
    csr_snd[pos] = snd[e];
}

// ---------------- fused pull-based GAT node update --------------------------
// TWO nodes per wave (one per 32-lane half; 8 nodes / 256-block).  Softmax
// over as_[senders] (receiver terms cancel), no max-shift in the common path
// (logits are O(5); exp cannot overflow).  deg<=32 path: csr/as_ gathered
// once into the half's registers, 5-level in-half reduce; feature loop does
// 2 edges/trip/node (16 lanes x uint4 = full 256B row per edge); 1-level
// combine; float4 stores.  Per-half generic 32-lane fallback for deg>32.
__global__ __launch_bounds__(256) void gat_node_kern(
    const unsigned* __restrict__ q_bfu, const float* __restrict__ as_,
    const int* __restrict__ rowptr, const int* __restrict__ csr_snd,
    float* __restrict__ xout, int N)
{
    const int lane = threadIdx.x & 63;
    const int l32  = lane & 31;
    const int base32 = lane & 32;          // 0 or 32 (half base)
    const int n = blockIdx.x * 8 + (threadIdx.x >> 5);
    if (n >= N) return;
    const int start = rowptr[n], end = rowptr[n + 1];
    const int deg = end - start;

    if (deg <= 32) {
        const int i = start + l32;
        const bool valid = i < end;
        const int   s_c = valid ? csr_snd[i] : 0;
        const float e = valid ? __expf(as_[s_c]) : 0.f;
        float d = e;
        #pragma unroll
        for (int o = 1; o < 32; o <<= 1) d += __shfl_xor(d, o, 64);   // in-half
        const float wgt = e * ((d > 0.f) ? (1.f / d) : 0.f);

        const int es = l32 >> 4;       // edge slot within half: 0..1
        const int ql = lane & 15;      // lane within edge group
        float4 accLo = make_float4(0.f, 0.f, 0.f, 0.f);
        float4 accHi = make_float4(0.f, 0.f, 0.f, 0.f);
        for (int kb = 0; kb < deg; kb += 2) {
            const int k = kb + es;
            const int idx = (k < deg) ? k : (deg - 1);
            const int   s    = __shfl(s_c, base32 + idx, 64);
            float       coef = __shfl(wgt, base32 + idx, 64);
            if (k >= deg) coef = 0.f;
            const uint4 pv = *(const uint4*)(q_bfu + (size_t)s * 64 + 4 * ql);
            accLo.x = fmaf(coef, bf_lo(pv.x), accLo.x);
            accHi.x = fmaf(coef, bf_hi(pv.x), accHi.x);
            accLo.y = fmaf(coef, bf_lo(pv.y), accLo.y);
            accHi.y = fmaf(coef, bf_hi(pv.y), accHi.y);
            accLo.z = fmaf(coef, bf_lo(pv.z), accLo.z);
            accHi.z = fmaf(coef, bf_hi(pv.z), accHi.z);
            accLo.w = fmaf(coef, bf_lo(pv.w), accLo.w);
            accHi.w = fmaf(coef, bf_hi(pv.w), accHi.w);
        }
        // combine the 2 edge slots (xor 16 — stays within the half)
        accLo.x += __shfl_xor(accLo.x, 16, 64);
        accLo.y += __shfl_xor(accLo.y, 16, 64);
        accLo.z += __shfl_xor(accLo.z, 16, 64);
        accLo.w += __shfl_xor(accLo.w, 16, 64);
        accHi.x += __shfl_xor(accHi.x, 16, 64);
        accHi.y += __shfl_xor(accHi.y, 16, 64);
        accHi.z += __shfl_xor(accHi.z, 16, 64);
        accHi.w += __shfl_xor(accHi.w, 16, 64);
        if (es == 0) {
            // lane ql holds uints u=4*ql..4*ql+3: lo -> cols c0..c0+3, hi -> +16
            const int c0 = (ql >> 2) * 32 + (ql & 3) * 4;
            float4 lo4, hi4;
            lo4.x = accLo.x > 0.f ? accLo.x : 0.01f * accLo.x;
            lo4.y = accLo.y > 0.f ? accLo.y : 0.01f * accLo.y;
            lo4.z = accLo.z > 0.f ? accLo.z : 0.01f * accLo.z;
            lo4.w = accLo.w > 0.f ? accLo.w : 0.01f * accLo.w;
            hi4.x = accHi.x > 0.f ? accHi.x : 0.01f * accHi.x;
            hi4.y = accHi.y > 0.f ? accHi.y : 0.01f * accHi.y;
            hi4.z = accHi.z > 0.f ? accHi.z : 0.01f * accHi.z;
            hi4.w = accHi.w > 0.f ? accHi.w : 0.01f * accHi.w;
            *(float4*)(xout + (size_t)n * FD + c0)      = lo4;
            *(float4*)(xout + (size_t)n * FD + c0 + 16) = hi4;
        }
    } else {
        // generic per-half fallback (rare): 3-pass with max-shift, 32 lanes
        float m = -3.4e38f;
        for (int i = start + l32; i < end; i += 32) m = fmaxf(m, as_[csr_snd[i]]);
        #pragma unroll
        for (int o = 1; o < 32; o <<= 1) m = fmaxf(m, __shfl_xor(m, o, 64));
        float d = 0.f;
        for (int i = start + l32; i < end; i += 32) d += __expf(as_[csr_snd[i]] - m);
        #pragma unroll
        for (int o = 1; o < 32; o <<= 1) d += __shfl_xor(d, o, 64);
        const float inv = (d > 0.f) ? (1.f / d) : 0.f;
        float ax0 = 0.f, ay0 = 0.f, ax1 = 0.f, ay1 = 0.f;
        for (int i = start; i < end; ++i) {
            const int s = csr_snd[i];
            const float coef = __expf(as_[s] - m) * inv;
            const uint2 pv = *(const uint2*)(q_bfu + (size_t)s * 64 + 2 * l32);
            ax0 = fmaf(coef, bf_lo(pv.x), ax0);
            ay0 = fmaf(coef, bf_hi(pv.x), ay0);
            ax1 = fmaf(coef, bf_lo(pv.y), ax1);
            ay1 = fmaf(coef, bf_hi(pv.y), ay1);
        }
        ax0 = ax0 > 0.f ? ax0 : 0.01f * ax0;
        ay0 = ay0 > 0.f ? ay0 : 0.01f * ay0;
        ax1 = ax1 > 0.f ? ax1 : 0.01f * ax1;
        ay1 = ay1 > 0.f ? ay1 : 0.01f * ay1;
        const int u0 = 2 * l32, u1 = u0 + 1;
        const int c00 = (u0 >> 4) * 32 + (u0 & 15);
        const int c10 = (u1 >> 4) * 32 + (u1 & 15);
        xout[(size_t)n * FD + c00]      = ax0;
        xout[(size_t)n * FD + c00 + 16] = ay0;
        xout[(size_t)n * FD + c10]      = ax1;
        xout[(size_t)n * FD + c10 + 16] = ay1;
    }
}

// agg[g] = sum of x rows with gidx==g (gidx sorted -> run-length accumulate)
__global__ __launch_bounds__(256) void agg_kern(
    const float* __restrict__ x, const int* __restrict__ gidx,
    float* __restrict__ agg, int N)
{
    const int c  = threadIdx.x & 127;
    const int rl = threadIdx.x >> 7;   // 0..1
    int n   = blockIdx.x * 128 + rl;
    int end = blockIdx.x * 128 + 128;
    if (end > N) end = N;
    float acc = 0.f; int curg = -1;
    for (; n < end; n += 2) {
        int g = gidx[n];
        if (g != curg) {
            if (curg >= 0) atomAddF(&agg[(size_t)curg * FD + c], acc);
            curg = g; acc = 0.f;
        }
        acc += x[(size_t)n * FD + c];
    }
    if (curg >= 0) atomAddF(&agg[(size_t)curg * FD + c], acc);
}

// g_out = concat([agg, globals]) @ Wg + bg.  One block per graph; 256 thr =
// 2 split-K halves x 128 output cols; Wg reads coalesced across cols.
__global__ __launch_bounds__(256) void glob_kern(
    const float* __restrict__ agg, const float* __restrict__ glb,
    const float* __restrict__ Wg, const float* __restrict__ bg,
    float* __restrict__ gout, int G)
{
    __shared__ float xv[256];
    __shared__ float part[128];
    const int g = blockIdx.x;
    const int t = threadIdx.x;
    if (t < 128) xv[t] = agg[(size_t)g * FD + t];
    else         xv[t] = glb[(size_t)g * FD + (t - 128)];
    __syncthreads();
    const int c = t & 127, half = t >> 7;
    const float* __restrict__ W = Wg + (size_t)half * FD * FD;
    const float* __restrict__ xh = xv + half * FD;
    float acc = 0.f;
    #pragma unroll 8
    for (int k = 0; k < FD; ++k)
        acc = fmaf(xh[k], W[(size_t)k * FD + c], acc);
    if (half == 1) part[c] = acc;
    __syncthreads();
    if (half == 0) gout[(size_t)g * FD + c] = acc + part[c] + bg[c];
}

extern "C" void kernel_launch(void* const* d_in, const int* in_sizes, int n_in,
                              void* d_out, int out_size, void* d_ws, size_t ws_size,
                              hipStream_t stream)
{
    const float* nodes    = (const float*)d_in[0];
    const float* globals_ = (const float*)d_in[1];
    const float* Wq       = (const float*)d_in[2];
    const float* bq       = (const float*)d_in[3];
    const float* Wa       = (const float*)d_in[4];
    const float* ba       = (const float*)d_in[5];  (void)ba;  // cancels in softmax
    const float* Wg       = (const float*)d_in[6];
    const float* bg       = (const float*)d_in[7];
    const int* senders    = (const int*)d_in[8];
    const int* receivers  = (const int*)d_in[9];
    const int* gidx       = (const int*)d_in[10];

    const int N    = in_sizes[0] / FD;
    const int G    = in_sizes[1] / FD;
    const int E    = in_sizes[8];
    const int HOPS = in_sizes[3] / FD;
    const int NB   = (N + 2047) / 2048;   // scan blocks

    // workspace layout
    float* ws = (float*)d_ws;
    size_t off = 0;
    unsigned* q_bfu = (unsigned*)ws;  off += (size_t)N * 64;   // packed bf16 q
    float* xbuf = ws + off;        off += (size_t)N * FD;
    float* agg  = ws + off;        off += (size_t)G * FD;
    float* as_  = ws + off;        off += N;
    int* deg     = (int*)(ws + off); off += N;
    int* rowptr  = (int*)(ws + off); off += N + 1;
    int* cursor  = (int*)(ws + off); off += N;
    int* bsum    = (int*)(ws + off); off += NB;
    int* csr_snd = (int*)(ws + off); off += E;
    off = (off + 3) & ~(size_t)3;                       // 16B-align for short8 loads
    unsigned short* wq_hi = (unsigned short*)(ws + off); off += (size_t)HOPS * 16384 / 2;
    unsigned short* wq_lo = (unsigned short*)(ws + off); off += (size_t)HOPS * 16384 / 2;

    float* xout_final = (float*)d_out;                  // N*FD
    float* gout = (float*)d_out + (size_t)N * FD;       // G*FD

    // ---- one-time prep: CSR (receivers identical across hops) + W bf16 frags
    hipMemsetAsync(deg, 0, (size_t)N * sizeof(int), stream);
    hipMemsetAsync(agg, 0, (size_t)G * FD * sizeof(float), stream);
    hist_kern<<<(E + 255) / 256, 256, 0, stream>>>(receivers, deg, E);
    scan1_kern<<<NB, 256, 0, stream>>>(deg, rowptr, bsum, N);
    scan2_kern<<<1, 64, 0, stream>>>(bsum, rowptr, NB, N, E);
    scan3_kern<<<(N + 255) / 256, 256, 0, stream>>>(rowptr, cursor, bsum, N);
    fill_kern<<<(E + 255) / 256, 256, 0, stream>>>(senders, receivers, cursor, csr_snd, E);
    const int wtot = HOPS * 2048;
    wprep_kern<<<(wtot + 255) / 256, 256, 0, stream>>>(Wq, wq_hi, wq_lo, wtot);

    const float* xin = nodes;
    for (int h = 0; h < HOPS; ++h) {
        float* xout = (h == HOPS - 1) ? xout_final : xbuf;
        const unsigned short* whi_h = wq_hi + (size_t)h * 16384;
        const unsigned short* wlo_h = wq_lo + (size_t)h * 16384;
        const float* bq_h = bq + (size_t)h * FD;
        const float* Wa_h = Wa + (size_t)h * 2 * FD;

        qkern_mfma<<<(N + 127) / 128, 256, 0, stream>>>(xin, whi_h, wlo_h, bq_h,
                                                        Wa_h, q_bfu, as_, N);
        gat_node_kern<<<(N + 7) / 8, 256, 0, stream>>>(q_bfu, as_, rowptr, csr_snd,
                                                       xout, N);
        xin = xout;
    }

    agg_kern<<<(N + 127) / 128, 256, 0, stream>>>(xin, gidx, agg, N);
    glob_kern<<<G, 256, 0, stream>>>(agg, globals_, Wg, bg, gout, G);
}

// Round 15
// 192.693 us; speedup vs baseline: 1.1694x; 1.0611x over previous
//
#include <hip/hip_runtime.h>
#include <hip/hip_bf16.h>
#include <cstddef>

#define FD 128   // feature dim D == H == 128

typedef __attribute__((ext_vector_type(8))) short short8v;   // 8 bf16 (4 VGPRs)
typedef __attribute__((ext_vector_type(4))) float f32x4;

__device__ __forceinline__ void atomAddF(float* p, float v) {
    unsafeAtomicAdd(p, v);   // HW global_atomic_add_f32 on gfx950
}

__device__ __forceinline__ unsigned short bf16_rne(float x) {
    unsigned u = __float_as_uint(x);
    return (unsigned short)((u + 0x7fffu + ((u >> 16) & 1u)) >> 16);
}

__device__ __forceinline__ float bf_lo(unsigned u) { return __uint_as_float(u << 16); }
__device__ __forceinline__ float bf_hi(unsigned u) { return __uint_as_float(u & 0xffff0000u); }

// ---- one-time W prep (+ deg zeroing folded in): Wq (fp32 [hop][k][col]) ->
// B-fragment-ordered bf16 hi/lo.  Fragment order: [hop][kk(4)][ct(8)][lane(64)][j(8)],
// element = W[kk*32 + (lane>>4)*8 + j][ct*16 + (lane&15)].
__global__ void wprep_kern(const float* __restrict__ Wq,
                           unsigned short* __restrict__ whi,
                           unsigned short* __restrict__ wlo, int total,
                           int* __restrict__ deg, int N)
{
    int t = blockIdx.x * blockDim.x + threadIdx.x;
    if (t < N) deg[t] = 0;                  // folded memset (hist runs after)
    if (t >= total) return;                 // total = HOPS*2048
    const int hop = t >> 11;
    const int kk  = (t >> 9) & 3;
    const int ct  = (t >> 6) & 7;
    const int l   = t & 63;
    const float* Wh = Wq + (size_t)hop * FD * FD;
    #pragma unroll
    for (int j = 0; j < 8; ++j) {
        float w = Wh[(size_t)(kk * 32 + (l >> 4) * 8 + j) * FD + ct * 16 + (l & 15)];
        unsigned short h = bf16_rne(w);
        float hf = __uint_as_float((unsigned)h << 16);
        whi[(size_t)t * 8 + j] = h;
        wlo[(size_t)t * 8 + j] = bf16_rne(w - hf);
    }
}

// ---- q = xin @ Wq[h] + bq[h] via bf16 MFMA.  A = bf16(x) single fragment.
// B hi/lo split for fp32-grade weights.  W fragments LDS-STAGED once per
// block; W-reuse: each wave computes 32 rows (two 16-row A strips) per B pair.
// Fused sender-logit as_ = q . Wa[:128]  (receiver term cancels in softmax).
// q emitted bf16-PACKED: q_bfu[row][u] holds cols c0=(u>>4)*32+(u&15) (lo),
// c0+16 (hi).
// Block: 256 thr = 4 waves; 128 rows/block; LDS 64KB -> 2 blocks/CU.
__global__ __launch_bounds__(256) void qkern_mfma(
    const float* __restrict__ xin,
    const unsigned short* __restrict__ whi, const unsigned short* __restrict__ wlo,
    const float* __restrict__ bq, const float* __restrict__ Wa,
    unsigned* __restrict__ q_bfu, float* __restrict__ as_, int N)
{
    __shared__ unsigned short lds_hi[16384];   // 32KB
    __shared__ unsigned short lds_lo[16384];   // 32KB

    const int t    = threadIdx.x;
    const int lane = t & 63;
    const int w    = t >> 6;                    // wave 0..3
    const int rowBase = blockIdx.x * 128 + w * 32;

    // cooperative stage: 8192 uint4 per table / 256 thr = 32 trips each
    {
        const uint4* src_hi = (const uint4*)whi;
        const uint4* src_lo = (const uint4*)wlo;
        uint4* dst_hi = (uint4*)lds_hi;
        uint4* dst_lo = (uint4*)lds_lo;
        #pragma unroll
        for (int i = 0; i < 8; ++i) {
            dst_hi[t + i * 256] = src_hi[t + i * 256];
            dst_lo[t + i * 256] = src_lo[t + i * 256];
        }
    }
    __syncthreads();
    if (rowBase >= N) return;

    const int kgrp = lane >> 4;                 // 0..3
    const int cidx = lane & 15;

    // A-rows for the two strips (clamped; OOB rows guarded at store)
    int arow0 = rowBase + cidx;       if (arow0 >= N) arow0 = N - 1;
    int arow1 = rowBase + 16 + cidx;  if (arow1 >= N) arow1 = N - 1;
    const float* __restrict__ xr0 = xin + (size_t)arow0 * FD;
    const float* __restrict__ xr1 = xin + (size_t)arow1 * FD;

    f32x4 acc0[8], acc1[8];
    #pragma unroll
    for (int ct = 0; ct < 8; ++ct) {
        acc0[ct] = (f32x4){0.f, 0.f, 0.f, 0.f};
        acc1[ct] = (f32x4){0.f, 0.f, 0.f, 0.f};
    }

    #pragma unroll
    for (int kk = 0; kk < 4; ++kk) {
        const int ko = kk * 32 + kgrp * 8;
        float4 x0a = *(const float4*)(xr0 + ko);
        float4 x0b = *(const float4*)(xr0 + ko + 4);
        float4 x1a = *(const float4*)(xr1 + ko);
        float4 x1b = *(const float4*)(xr1 + ko + 4);
        float v0[8] = {x0a.x, x0a.y, x0a.z, x0a.w, x0b.x, x0b.y, x0b.z, x0b.w};
        float v1[8] = {x1a.x, x1a.y, x1a.z, x1a.w, x1b.x, x1b.y, x1b.z, x1b.w};
        short8v a0, a1;
        #pragma unroll
        for (int j = 0; j < 8; ++j) {
            a0[j] = (short)bf16_rne(v0[j]);
            a1[j] = (short)bf16_rne(v1[j]);
        }
        #pragma unroll
        for (int ct = 0; ct < 8; ++ct) {
            const int fo = ((kk * 8 + ct) * 64 + lane) * 8;
            short8v bhi = *(const short8v*)(lds_hi + fo);
            short8v blo = *(const short8v*)(lds_lo + fo);
            acc0[ct] = __builtin_amdgcn_mfma_f32_16x16x32_bf16(a0, bhi, acc0[ct], 0, 0, 0);
            acc0[ct] = __builtin_amdgcn_mfma_f32_16x16x32_bf16(a0, blo, acc0[ct], 0, 0, 0);
            acc1[ct] = __builtin_amdgcn_mfma_f32_16x16x32_bf16(a1, bhi, acc1[ct], 0, 0, 0);
            acc1[ct] = __builtin_amdgcn_mfma_f32_16x16x32_bf16(a1, blo, acc1[ct], 0, 0, 0);
        }
    }

    // epilogue: bias, packed-bf16 q store, fused as_ dot — per row strip
    float bqv[8], wav[8];
    #pragma unroll
    for (int ct = 0; ct < 8; ++ct) {
        bqv[ct] = bq[ct * 16 + cidx];
        wav[ct] = Wa[ct * 16 + cidx];
    }
    #pragma unroll
    for (int strip = 0; strip < 2; ++strip) {
        const f32x4* acc = strip ? acc1 : acc0;
        const int sbase = rowBase + strip * 16;
        #pragma unroll
        for (int j = 0; j < 4; ++j) {
            const int row = sbase + kgrp * 4 + j;    // C/D: row=(lane>>4)*4+reg
            const bool ok = row < N;
            float p = 0.f;
            float vv[8];
            #pragma unroll
            for (int ct = 0; ct < 8; ++ct) {
                vv[ct] = acc[ct][j] + bqv[ct];
                p = fmaf(vv[ct], wav[ct], p);
            }
            if (ok) {
                unsigned* qrow = q_bfu + (size_t)row * 64;
                #pragma unroll
                for (int tp = 0; tp < 4; ++tp) {
                    unsigned lo = bf16_rne(vv[2 * tp]);        // col tp*32+cidx
                    unsigned hi = bf16_rne(vv[2 * tp + 1]);    // col tp*32+16+cidx
                    qrow[tp * 16 + cidx] = lo | (hi << 16);
                }
            }
            p += __shfl_xor(p, 1, 64);
            p += __shfl_xor(p, 2, 64);
            p += __shfl_xor(p, 4, 64);
            p += __shfl_xor(p, 8, 64);
            if (ok && cidx == 0) as_[row] = p;
        }
    }
}

// ---------------- CSR build (once; receivers are hop-invariant) -------------
__global__ void hist_kern(const int* __restrict__ rcv, int* __restrict__ deg, int E) {
    int e = blockIdx.x * blockDim.x + threadIdx.x;
    if (e < E) atomicAdd(&deg[rcv[e]], 1);
}

// hierarchical exclusive scan, phase 1: 2048 elems/block, wave-shuffle scan.
__global__ __launch_bounds__(256) void scan1_kern(
    const int* __restrict__ deg, int* __restrict__ rowptr,
    int* __restrict__ bsum, int N)
{
    const int t = threadIdx.x;
    const int base = blockIdx.x * 2048 + t * 8;
    int v[8]; int s = 0;
    #pragma unroll
    for (int j = 0; j < 8; ++j) {
        v[j] = (base + j < N) ? deg[base + j] : 0;
        s += v[j];
    }
    const int lane = t & 63;
    const int wv = t >> 6;   // 0..3
    int incl = s;
    #pragma unroll
    for (int o = 1; o < 64; o <<= 1) {
        int x = __shfl_up(incl, o, 64);
        if (lane >= o) incl += x;
    }
    __shared__ int wsum[4];
    if (lane == 63) wsum[wv] = incl;
    __syncthreads();
    int woff = 0;
    #pragma unroll
    for (int w = 0; w < 4; ++w) woff += (w < wv) ? wsum[w] : 0;
    int excl = woff + incl - s;
    #pragma unroll
    for (int j = 0; j < 8; ++j) {
        if (base + j < N) rowptr[base + j] = excl;
        excl += v[j];
    }
    if (t == 255) bsum[blockIdx.x] = woff + incl;
}

// phase 2: single wave scans block sums (exclusive, in place); writes rowptr[N].
__global__ void scan2_kern(int* __restrict__ bsum, int* __restrict__ rowptr,
                           int nb, int N, int E)
{
    const int lane = threadIdx.x;   // 64 threads
    int carry = 0;
    for (int c = 0; c < nb; c += 64) {
        int i = c + lane;
        int v = (i < nb) ? bsum[i] : 0;
        int incl = v;
        #pragma unroll
        for (int o = 1; o < 64; o <<= 1) {
            int x = __shfl_up(incl, o, 64);
            if (lane >= o) incl += x;
        }
        if (i < nb) bsum[i] = carry + incl - v;
        carry += __shfl(incl, 63, 64);
    }
    if (lane == 0) rowptr[N] = E;
}

// phase 3: add block offsets; fill cursor copy; zero agg (folded memset).
__global__ void scan3_kern(int* __restrict__ rowptr, int* __restrict__ cursor,
                           const int* __restrict__ bsum, int N,
                           float* __restrict__ agg, int aggN)
{
    int i = blockIdx.x * blockDim.x + threadIdx.x;
    if (i < aggN) agg[i] = 0.f;     // agg only written much later (agg_kern)
    if (i >= N) return;
    int v = rowptr[i] + bsum[i >> 11];
    rowptr[i] = v;
    cursor[i] = v;
}

__global__ void fill_kern(const int* __restrict__ snd, const int* __restrict__ rcv,
                          int* __restrict__ cursor, int* __restrict__ csr_snd, int E)
{
    int e = blockIdx.x * blockDim.x + threadIdx.x;
    if (e >= E) return;
    int pos = atomicAdd(&cursor[rcv[e]], 1);
    csr_snd[pos] = snd[e];
}

// ---------------- fused pull-based GAT node update --------------------------
// TWO nodes per wave (one per 32-lane half; 8 nodes / 256-block).  Softmax
// over as_[senders] (receiver terms cancel), no max-shift in the common path
// (logits are O(5); exp cannot overflow).  deg<=32 path: csr/as_ gathered
// once into the half's registers, 5-level in-half reduce.  Feature loop:
// 4 EDGES per trip per node — each lane issues TWO independent uint4 loads
// (edge slots es and es+2) to keep 4 gathers in flight (R14 lesson: the
// gather dependency chain, not instruction count, limits this kernel).
// 1-level combine; float4 stores.  Per-half 32-lane fallback for deg>32.
__global__ __launch_bounds__(256) void gat_node_kern(
    const unsigned* __restrict__ q_bfu, const float* __restrict__ as_,
    const int* __restrict__ rowptr, const int* __restrict__ csr_snd,
    float* __restrict__ xout, int N)
{
    const int lane = threadIdx.x & 63;
    const int l32  = lane & 31;
    const int base32 = lane & 32;          // 0 or 32 (half base)
    const int n = blockIdx.x * 8 + (threadIdx.x >> 5);
    if (n >= N) return;
    const int start = rowptr[n], end = rowptr[n + 1];
    const int deg = end - start;

    if (deg <= 32) {
        const int i = start + l32;
        const bool valid = i < end;
        const int   s_c = valid ? csr_snd[i] : 0;
        const float e = valid ? __expf(as_[s_c]) : 0.f;
        float d = e;
        #pragma unroll
        for (int o = 1; o < 32; o <<= 1) d += __shfl_xor(d, o, 64);   // in-half
        const float wgt = e * ((d > 0.f) ? (1.f / d) : 0.f);

        const int es = l32 >> 4;       // edge slot within half: 0..1
        const int ql = lane & 15;      // lane within edge group
        float4 accLo = make_float4(0.f, 0.f, 0.f, 0.f);
        float4 accHi = make_float4(0.f, 0.f, 0.f, 0.f);
        for (int kb = 0; kb < deg; kb += 4) {
            const int k0 = kb + es;
            const int k1 = kb + es + 2;
            const int i0 = (k0 < deg) ? k0 : (deg - 1);
            const int i1 = (k1 < deg) ? k1 : (deg - 1);
            const int   s0 = __shfl(s_c, base32 + i0, 64);
            float       c0 = __shfl(wgt, base32 + i0, 64);
            const int   s1 = __shfl(s_c, base32 + i1, 64);
            float       c1 = __shfl(wgt, base32 + i1, 64);
            if (k0 >= deg) c0 = 0.f;
            if (k1 >= deg) c1 = 0.f;
            const uint4 p0 = *(const uint4*)(q_bfu + (size_t)s0 * 64 + 4 * ql);
            const uint4 p1 = *(const uint4*)(q_bfu + (size_t)s1 * 64 + 4 * ql);
            accLo.x = fmaf(c0, bf_lo(p0.x), accLo.x);
            accHi.x = fmaf(c0, bf_hi(p0.x), accHi.x);
            accLo.y = fmaf(c0, bf_lo(p0.y), accLo.y);
            accHi.y = fmaf(c0, bf_hi(p0.y), accHi.y);
            accLo.z = fmaf(c0, bf_lo(p0.z), accLo.z);
            accHi.z = fmaf(c0, bf_hi(p0.z), accHi.z);
            accLo.w = fmaf(c0, bf_lo(p0.w), accLo.w);
            accHi.w = fmaf(c0, bf_hi(p0.w), accHi.w);
            accLo.x = fmaf(c1, bf_lo(p1.x), accLo.x);
            accHi.x = fmaf(c1, bf_hi(p1.x), accHi.x);
            accLo.y = fmaf(c1, bf_lo(p1.y), accLo.y);
            accHi.y = fmaf(c1, bf_hi(p1.y), accHi.y);
            accLo.z = fmaf(c1, bf_lo(p1.z), accLo.z);
            accHi.z = fmaf(c1, bf_hi(p1.z), accHi.z);
            accLo.w = fmaf(c1, bf_lo(p1.w), accLo.w);
            accHi.w = fmaf(c1, bf_hi(p1.w), accHi.w);
        }
        // combine the 2 edge slots (xor 16 — stays within the half)
        accLo.x += __shfl_xor(accLo.x, 16, 64);
        accLo.y += __shfl_xor(accLo.y, 16, 64);
        accLo.z += __shfl_xor(accLo.z, 16, 64);
        accLo.w += __shfl_xor(accLo.w, 16, 64);
        accHi.x += __shfl_xor(accHi.x, 16, 64);
        accHi.y += __shfl_xor(accHi.y, 16, 64);
        accHi.z += __shfl_xor(accHi.z, 16, 64);
        accHi.w += __shfl_xor(accHi.w, 16, 64);
        if (es == 0) {
            // lane ql holds uints u=4*ql..4*ql+3: lo -> cols c0..c0+3, hi -> +16
            const int c0 = (ql >> 2) * 32 + (ql & 3) * 4;
            float4 lo4, hi4;
            lo4.x = accLo.x > 0.f ? accLo.x : 0.01f * accLo.x;
            lo4.y = accLo.y > 0.f ? accLo.y : 0.01f * accLo.y;
            lo4.z = accLo.z > 0.f ? accLo.z : 0.01f * accLo.z;
            lo4.w = accLo.w > 0.f ? accLo.w : 0.01f * accLo.w;
            hi4.x = accHi.x > 0.f ? accHi.x : 0.01f * accHi.x;
            hi4.y = accHi.y > 0.f ? accHi.y : 0.01f * accHi.y;
            hi4.z = accHi.z > 0.f ? accHi.z : 0.01f * accHi.z;
            hi4.w = accHi.w > 0.f ? accHi.w : 0.01f * accHi.w;
            *(float4*)(xout + (size_t)n * FD + c0)      = lo4;
            *(float4*)(xout + (size_t)n * FD + c0 + 16) = hi4;
        }
    } else {
        // generic per-half fallback (rare): 3-pass with max-shift, 32 lanes
        float m = -3.4e38f;
        for (int i = start + l32; i < end; i += 32) m = fmaxf(m, as_[csr_snd[i]]);
        #pragma unroll
        for (int o = 1; o < 32; o <<= 1) m = fmaxf(m, __shfl_xor(m, o, 64));
        float d = 0.f;
        for (int i = start + l32; i < end; i += 32) d += __expf(as_[csr_snd[i]] - m);
        #pragma unroll
        for (int o = 1; o < 32; o <<= 1) d += __shfl_xor(d, o, 64);
        const float inv = (d > 0.f) ? (1.f / d) : 0.f;
        float ax0 = 0.f, ay0 = 0.f, ax1 = 0.f, ay1 = 0.f;
        for (int i = start; i < end; ++i) {
            const int s = csr_snd[i];
            const float coef = __expf(as_[s] - m) * inv;
            const uint2 pv = *(const uint2*)(q_bfu + (size_t)s * 64 + 2 * l32);
            ax0 = fmaf(coef, bf_lo(pv.x), ax0);
            ay0 = fmaf(coef, bf_hi(pv.x), ay0);
            ax1 = fmaf(coef, bf_lo(pv.y), ax1);
            ay1 = fmaf(coef, bf_hi(pv.y), ay1);
        }
        ax0 = ax0 > 0.f ? ax0 : 0.01f * ax0;
        ay0 = ay0 > 0.f ? ay0 : 0.01f * ay0;
        ax1 = ax1 > 0.f ? ax1 : 0.01f * ax1;
        ay1 = ay1 > 0.f ? ay1 : 0.01f * ay1;
        const int u0 = 2 * l32, u1 = u0 + 1;
        const int c00 = (u0 >> 4) * 32 + (u0 & 15);
        const int c10 = (u1 >> 4) * 32 + (u1 & 15);
        xout[(size_t)n * FD + c00]      = ax0;
        xout[(size_t)n * FD + c00 + 16] = ay0;
        xout[(size_t)n * FD + c10]      = ax1;
        xout[(size_t)n * FD + c10 + 16] = ay1;
    }
}

// agg[g] = sum of x rows with gidx==g (gidx sorted -> run-length accumulate)
__global__ __launch_bounds__(256) void agg_kern(
    const float* __restrict__ x, const int* __restrict__ gidx,
    float* __restrict__ agg, int N)
{
    const int c  = threadIdx.x & 127;
    const int rl = threadIdx.x >> 7;   // 0..1
    int n   = blockIdx.x * 128 + rl;
    int end = blockIdx.x * 128 + 128;
    if (end > N) end = N;
    float acc = 0.f; int curg = -1;
    for (; n < end; n += 2) {
        int g = gidx[n];
        if (g != curg) {
            if (curg >= 0) atomAddF(&agg[(size_t)curg * FD + c], acc);
            curg = g; acc = 0.f;
        }
        acc += x[(size_t)n * FD + c];
    }
    if (curg >= 0) atomAddF(&agg[(size_t)curg * FD + c], acc);
}

// g_out = concat([agg, globals]) @ Wg + bg.  One block per graph; 256 thr =
// 2 split-K halves x 128 output cols; Wg reads coalesced across cols.
__global__ __launch_bounds__(256) void glob_kern(
    const float* __restrict__ agg, const float* __restrict__ glb,
    const float* __restrict__ Wg, const float* __restrict__ bg,
    float* __restrict__ gout, int G)
{
    __shared__ float xv[256];
    __shared__ float part[128];
    const int g = blockIdx.x;
    const int t = threadIdx.x;
    if (t < 128) xv[t] = agg[(size_t)g * FD + t];
    else         xv[t] = glb[(size_t)g * FD + (t - 128)];
    __syncthreads();
    const int c = t & 127, half = t >> 7;
    const float* __restrict__ W = Wg + (size_t)half * FD * FD;
    const float* __restrict__ xh = xv + half * FD;
    float acc = 0.f;
    #pragma unroll 8
    for (int k = 0; k < FD; ++k)
        acc = fmaf(xh[k], W[(size_t)k * FD + c], acc);
    if (half == 1) part[c] = acc;
    __syncthreads();
    if (half == 0) gout[(size_t)g * FD + c] = acc + part[c] + bg[c];
}

extern "C" void kernel_launch(void* const* d_in, const int* in_sizes, int n_in,
                              void* d_out, int out_size, void* d_ws, size_t ws_size,
                              hipStream_t stream)
{
    const float* nodes    = (const float*)d_in[0];
    const float* globals_ = (const float*)d_in[1];
    const float* Wq       = (const float*)d_in[2];
    const float* bq       = (const float*)d_in[3];
    const float* Wa       = (const float*)d_in[4];
    const float* ba       = (const float*)d_in[5];  (void)ba;  // cancels in softmax
    const float* Wg       = (const float*)d_in[6];
    const float* bg       = (const float*)d_in[7];
    const int* senders    = (const int*)d_in[8];
    const int* receivers  = (const int*)d_in[9];
    const int* gidx       = (const int*)d_in[10];

    const int N    = in_sizes[0] / FD;
    const int G    = in_sizes[1] / FD;
    const int E    = in_sizes[8];
    const int HOPS = in_sizes[3] / FD;
    const int NB   = (N + 2047) / 2048;   // scan blocks

    // workspace layout
    float* ws = (float*)d_ws;
    size_t off = 0;
    unsigned* q_bfu = (unsigned*)ws;  off += (size_t)N * 64;   // packed bf16 q
    float* xbuf = ws + off;        off += (size_t)N * FD;
    float* agg  = ws + off;        off += (size_t)G * FD;
    float* as_  = ws + off;        off += N;
    int* deg     = (int*)(ws + off); off += N;
    int* rowptr  = (int*)(ws + off); off += N + 1;
    int* cursor  = (int*)(ws + off); off += N;
    int* bsum    = (int*)(ws + off); off += NB;
    int* csr_snd = (int*)(ws + off); off += E;
    off = (off + 3) & ~(size_t)3;                       // 16B-align for short8 loads
    unsigned short* wq_hi = (unsigned short*)(ws + off); off += (size_t)HOPS * 16384 / 2;
    unsigned short* wq_lo = (unsigned short*)(ws + off); off += (size_t)HOPS * 16384 / 2;

    float* xout_final = (float*)d_out;                  // N*FD
    float* gout = (float*)d_out + (size_t)N * FD;       // G*FD

    // ---- one-time prep: W frags + deg zero (fused), CSR, agg zero (fused)
    const int wtot = HOPS * 2048;
    const int wgrid = (((N > wtot) ? N : wtot) + 255) / 256;
    wprep_kern<<<wgrid, 256, 0, stream>>>(Wq, wq_hi, wq_lo, wtot, deg, N);
    hist_kern<<<(E + 255) / 256, 256, 0, stream>>>(receivers, deg, E);
    scan1_kern<<<NB, 256, 0, stream>>>(deg, rowptr, bsum, N);
    scan2_kern<<<1, 64, 0, stream>>>(bsum, rowptr, NB, N, E);
    scan3_kern<<<(N + 255) / 256, 256, 0, stream>>>(rowptr, cursor, bsum, N,
                                                    agg, G * FD);
    fill_kern<<<(E + 255) / 256, 256, 0, stream>>>(senders, receivers, cursor, csr_snd, E);

    const float* xin = nodes;
    for (int h = 0; h < HOPS; ++h) {
        float* xout = (h == HOPS - 1) ? xout_final : xbuf;
        const unsigned short* whi_h = wq_hi + (size_t)h * 16384;
        const unsigned short* wlo_h = wq_lo + (size_t)h * 16384;
        const float* bq_h = bq + (size_t)h * FD;
        const float* Wa_h = Wa + (size_t)h * 2 * FD;

        qkern_mfma<<<(N + 127) / 128, 256, 0, stream>>>(xin, whi_h, wlo_h, bq_h,
                                                        Wa_h, q_bfu, as_, N);
        gat_node_kern<<<(N + 7) / 8, 256, 0, stream>>>(q_bfu, as_, rowptr, csr_snd,
                                                       xout, N);
        xin = xout;
    }

    agg_kern<<<(N + 127) / 128, 256, 0, stream>>>(xin, gidx, agg, N);
    glob_kern<<<G, 256, 0, stream>>>(agg, globals_, Wg, bg, gout, G);
}

// Round 16
// 189.699 us; speedup vs baseline: 1.1878x; 1.0158x over previous
//
#include <hip/hip_runtime.h>
#include <hip/hip_bf16.h>
#include <cstddef>

#define FD 128   // feature dim D == H == 128

typedef __attribute__((ext_vector_type(8))) short short8v;   // 8 bf16 (4 VGPRs)
typedef __attribute__((ext_vector_type(4))) float f32x4;

__device__ __forceinline__ void atomAddF(float* p, float v) {
    unsafeAtomicAdd(p, v);   // HW global_atomic_add_f32 on gfx950
}

__device__ __forceinline__ unsigned short bf16_rne(float x) {
    unsigned u = __float_as_uint(x);
    return (unsigned short)((u + 0x7fffu + ((u >> 16) & 1u)) >> 16);
}

__device__ __forceinline__ float bf_lo(unsigned u) { return __uint_as_float(u << 16); }
__device__ __forceinline__ float bf_hi(unsigned u) { return __uint_as_float(u & 0xffff0000u); }

// ---- one-time W prep (+ deg zeroing folded in): Wq (fp32 [hop][k][col]) ->
// B-fragment-ordered bf16 hi/lo.  Fragment order: [hop][kk(4)][ct(8)][lane(64)][j(8)],
// element = W[kk*32 + (lane>>4)*8 + j][ct*16 + (lane&15)].
__global__ void wprep_kern(const float* __restrict__ Wq,
                           unsigned short* __restrict__ whi,
                           unsigned short* __restrict__ wlo, int total,
                           int* __restrict__ deg, int N)
{
    int t = blockIdx.x * blockDim.x + threadIdx.x;
    if (t < N) deg[t] = 0;                  // folded memset (hist runs after)
    if (t >= total) return;                 // total = HOPS*2048
    const int hop = t >> 11;
    const int kk  = (t >> 9) & 3;
    const int ct  = (t >> 6) & 7;
    const int l   = t & 63;
    const float* Wh = Wq + (size_t)hop * FD * FD;
    #pragma unroll
    for (int j = 0; j < 8; ++j) {
        float w = Wh[(size_t)(kk * 32 + (l >> 4) * 8 + j) * FD + ct * 16 + (l & 15)];
        unsigned short h = bf16_rne(w);
        float hf = __uint_as_float((unsigned)h << 16);
        whi[(size_t)t * 8 + j] = h;
        wlo[(size_t)t * 8 + j] = bf16_rne(w - hf);
    }
}

// ---- q = xin @ Wq[h] + bq[h] via bf16 MFMA.  A = bf16(x) single fragment.
// B hi/lo split for fp32-grade weights.  W fragments LDS-STAGED once per
// block; W-reuse: each wave computes 32 rows (two 16-row A strips) per B pair.
// Fused sender-logit as_ = q . Wa[:128]  (receiver term cancels in softmax).
// q emitted bf16-PACKED: q_bfu[row][u] holds cols c0=(u>>4)*32+(u&15) (lo),
// c0+16 (hi).
// Block: 256 thr = 4 waves; 128 rows/block; LDS 64KB -> 2 blocks/CU.
__global__ __launch_bounds__(256) void qkern_mfma(
    const float* __restrict__ xin,
    const unsigned short* __restrict__ whi, const unsigned short* __restrict__ wlo,
    const float* __restrict__ bq, const float* __restrict__ Wa,
    unsigned* __restrict__ q_bfu, float* __restrict__ as_, int N)
{
    __shared__ unsigned short lds_hi[16384];   // 32KB
    __shared__ unsigned short lds_lo[16384];   // 32KB

    const int t    = threadIdx.x;
    const int lane = t & 63;
    const int w    = t >> 6;                    // wave 0..3
    const int rowBase = blockIdx.x * 128 + w * 32;

    // cooperative stage: 8192 uint4 per table / 256 thr = 32 trips each
    {
        const uint4* src_hi = (const uint4*)whi;
        const uint4* src_lo = (const uint4*)wlo;
        uint4* dst_hi = (uint4*)lds_hi;
        uint4* dst_lo = (uint4*)lds_lo;
        #pragma unroll
        for (int i = 0; i < 8; ++i) {
            dst_hi[t + i * 256] = src_hi[t + i * 256];
            dst_lo[t + i * 256] = src_lo[t + i * 256];
        }
    }
    __syncthreads();
    if (rowBase >= N) return;

    const int kgrp = lane >> 4;                 // 0..3
    const int cidx = lane & 15;

    // A-rows for the two strips (clamped; OOB rows guarded at store)
    int arow0 = rowBase + cidx;       if (arow0 >= N) arow0 = N - 1;
    int arow1 = rowBase + 16 + cidx;  if (arow1 >= N) arow1 = N - 1;
    const float* __restrict__ xr0 = xin + (size_t)arow0 * FD;
    const float* __restrict__ xr1 = xin + (size_t)arow1 * FD;

    f32x4 acc0[8], acc1[8];
    #pragma unroll
    for (int ct = 0; ct < 8; ++ct) {
        acc0[ct] = (f32x4){0.f, 0.f, 0.f, 0.f};
        acc1[ct] = (f32x4){0.f, 0.f, 0.f, 0.f};
    }

    #pragma unroll
    for (int kk = 0; kk < 4; ++kk) {
        const int ko = kk * 32 + kgrp * 8;
        float4 x0a = *(const float4*)(xr0 + ko);
        float4 x0b = *(const float4*)(xr0 + ko + 4);
        float4 x1a = *(const float4*)(xr1 + ko);
        float4 x1b = *(const float4*)(xr1 + ko + 4);
        float v0[8] = {x0a.x, x0a.y, x0a.z, x0a.w, x0b.x, x0b.y, x0b.z, x0b.w};
        float v1[8] = {x1a.x, x1a.y, x1a.z, x1a.w, x1b.x, x1b.y, x1b.z, x1b.w};
        short8v a0, a1;
        #pragma unroll
        for (int j = 0; j < 8; ++j) {
            a0[j] = (short)bf16_rne(v0[j]);
            a1[j] = (short)bf16_rne(v1[j]);
        }
        #pragma unroll
        for (int ct = 0; ct < 8; ++ct) {
            const int fo = ((kk * 8 + ct) * 64 + lane) * 8;
            short8v bhi = *(const short8v*)(lds_hi + fo);
            short8v blo = *(const short8v*)(lds_lo + fo);
            acc0[ct] = __builtin_amdgcn_mfma_f32_16x16x32_bf16(a0, bhi, acc0[ct], 0, 0, 0);
            acc0[ct] = __builtin_amdgcn_mfma_f32_16x16x32_bf16(a0, blo, acc0[ct], 0, 0, 0);
            acc1[ct] = __builtin_amdgcn_mfma_f32_16x16x32_bf16(a1, bhi, acc1[ct], 0, 0, 0);
            acc1[ct] = __builtin_amdgcn_mfma_f32_16x16x32_bf16(a1, blo, acc1[ct], 0, 0, 0);
        }
    }

    // epilogue: bias, packed-bf16 q store, fused as_ dot — per row strip
    float bqv[8], wav[8];
    #pragma unroll
    for (int ct = 0; ct < 8; ++ct) {
        bqv[ct] = bq[ct * 16 + cidx];
        wav[ct] = Wa[ct * 16 + cidx];
    }
    #pragma unroll
    for (int strip = 0; strip < 2; ++strip) {
        const f32x4* acc = strip ? acc1 : acc0;
        const int sbase = rowBase + strip * 16;
        #pragma unroll
        for (int j = 0; j < 4; ++j) {
            const int row = sbase + kgrp * 4 + j;    // C/D: row=(lane>>4)*4+reg
            const bool ok = row < N;
            float p = 0.f;
            float vv[8];
            #pragma unroll
            for (int ct = 0; ct < 8; ++ct) {
                vv[ct] = acc[ct][j] + bqv[ct];
                p = fmaf(vv[ct], wav[ct], p);
            }
            if (ok) {
                unsigned* qrow = q_bfu + (size_t)row * 64;
                #pragma unroll
                for (int tp = 0; tp < 4; ++tp) {
                    unsigned lo = bf16_rne(vv[2 * tp]);        // col tp*32+cidx
                    unsigned hi = bf16_rne(vv[2 * tp + 1]);    // col tp*32+16+cidx
                    qrow[tp * 16 + cidx] = lo | (hi << 16);
                }
            }
            p += __shfl_xor(p, 1, 64);
            p += __shfl_xor(p, 2, 64);
            p += __shfl_xor(p, 4, 64);
            p += __shfl_xor(p, 8, 64);
            if (ok && cidx == 0) as_[row] = p;
        }
    }
}

// ---------------- CSR build (once; receivers are hop-invariant) -------------
__global__ void hist_kern(const int* __restrict__ rcv, int* __restrict__ deg, int E) {
    int e = blockIdx.x * blockDim.x + threadIdx.x;
    if (e < E) atomicAdd(&deg[rcv[e]], 1);
}

// hierarchical exclusive scan, phase 1: 2048 elems/block, wave-shuffle scan.
__global__ __launch_bounds__(256) void scan1_kern(
    const int* __restrict__ deg, int* __restrict__ rowptr,
    int* __restrict__ bsum, int N)
{
    const int t = threadIdx.x;
    const int base = blockIdx.x * 2048 + t * 8;
    int v[8]; int s = 0;
    #pragma unroll
    for (int j = 0; j < 8; ++j) {
        v[j] = (base + j < N) ? deg[base + j] : 0;
        s += v[j];
    }
    const int lane = t & 63;
    const int wv = t >> 6;   // 0..3
    int incl = s;
    #pragma unroll
    for (int o = 1; o < 64; o <<= 1) {
        int x = __shfl_up(incl, o, 64);
        if (lane >= o) incl += x;
    }
    __shared__ int wsum[4];
    if (lane == 63) wsum[wv] = incl;
    __syncthreads();
    int woff = 0;
    #pragma unroll
    for (int w = 0; w < 4; ++w) woff += (w < wv) ? wsum[w] : 0;
    int excl = woff + incl - s;
    #pragma unroll
    for (int j = 0; j < 8; ++j) {
        if (base + j < N) rowptr[base + j] = excl;
        excl += v[j];
    }
    if (t == 255) bsum[blockIdx.x] = woff + incl;
}

// phase 2: single wave scans block sums (exclusive, in place); writes rowptr[N].
__global__ void scan2_kern(int* __restrict__ bsum, int* __restrict__ rowptr,
                           int nb, int N, int E)
{
    const int lane = threadIdx.x;   // 64 threads
    int carry = 0;
    for (int c = 0; c < nb; c += 64) {
        int i = c + lane;
        int v = (i < nb) ? bsum[i] : 0;
        int incl = v;
        #pragma unroll
        for (int o = 1; o < 64; o <<= 1) {
            int x = __shfl_up(incl, o, 64);
            if (lane >= o) incl += x;
        }
        if (i < nb) bsum[i] = carry + incl - v;
        carry += __shfl(incl, 63, 64);
    }
    if (lane == 0) rowptr[N] = E;
}

// phase 3: add block offsets; fill cursor copy; zero agg (folded memset).
__global__ void scan3_kern(int* __restrict__ rowptr, int* __restrict__ cursor,
                           const int* __restrict__ bsum, int N,
                           float* __restrict__ agg, int aggN)
{
    int i = blockIdx.x * blockDim.x + threadIdx.x;
    if (i < aggN) agg[i] = 0.f;     // agg only written much later (agg_kern)
    if (i >= N) return;
    int v = rowptr[i] + bsum[i >> 11];
    rowptr[i] = v;
    cursor[i] = v;
}

__global__ void fill_kern(const int* __restrict__ snd, const int* __restrict__ rcv,
                          int* __restrict__ cursor, int* __restrict__ csr_snd, int E)
{
    int e = blockIdx.x * blockDim.x + threadIdx.x;
    if (e >= E) return;
    int pos = atomicAdd(&cursor[rcv[e]], 1);
    csr_snd[pos] = snd[e];
}

// ---------------- fused pull-based GAT node update --------------------------
// TWO nodes per wave (one per 32-lane half; 8 nodes / 256-block).  Softmax
// over as_[senders] (receiver terms cancel), no max-shift in the common path
// (logits are O(5); exp cannot overflow).  deg<=32 path: csr/as_ gathered
// once into the half's registers, 5-level in-half reduce.  Feature loop:
// 8 EDGES per trip per node — each lane issues FOUR independent uint4 loads
// (slots es, es+2, es+4, es+6) so a typical deg<=8 node finishes its gather
// in ONE round with 4 loads in flight (R14/R15 lesson: gather depth, not
// instruction count, is the limiter).  1-level combine; float4 stores.
// Per-half 32-lane fallback for deg>32.
__global__ __launch_bounds__(256) void gat_node_kern(
    const unsigned* __restrict__ q_bfu, const float* __restrict__ as_,
    const int* __restrict__ rowptr, const int* __restrict__ csr_snd,
    float* __restrict__ xout, int N)
{
    const int lane = threadIdx.x & 63;
    const int l32  = lane & 31;
    const int base32 = lane & 32;          // 0 or 32 (half base)
    const int n = blockIdx.x * 8 + (threadIdx.x >> 5);
    if (n >= N) return;
    const int start = rowptr[n], end = rowptr[n + 1];
    const int deg = end - start;

    if (deg <= 32) {
        const int i = start + l32;
        const bool valid = i < end;
        const int   s_c = valid ? csr_snd[i] : 0;
        const float e = valid ? __expf(as_[s_c]) : 0.f;
        float d = e;
        #pragma unroll
        for (int o = 1; o < 32; o <<= 1) d += __shfl_xor(d, o, 64);   // in-half
        const float wgt = e * ((d > 0.f) ? (1.f / d) : 0.f);

        const int es = l32 >> 4;       // edge slot within half: 0..1
        const int ql = lane & 15;      // lane within edge group
        float4 accLo = make_float4(0.f, 0.f, 0.f, 0.f);
        float4 accHi = make_float4(0.f, 0.f, 0.f, 0.f);
        for (int kb = 0; kb < deg; kb += 8) {
            int   kv[4];
            int   sv[4];
            float cv[4];
            #pragma unroll
            for (int u = 0; u < 4; ++u) {
                const int k = kb + es + 2 * u;
                const int idx = (k < deg) ? k : (deg - 1);
                kv[u] = k;
                sv[u] = __shfl(s_c, base32 + idx, 64);
                cv[u] = __shfl(wgt, base32 + idx, 64);
                if (k >= deg) cv[u] = 0.f;
            }
            uint4 pv[4];
            #pragma unroll
            for (int u = 0; u < 4; ++u)
                pv[u] = *(const uint4*)(q_bfu + (size_t)sv[u] * 64 + 4 * ql);
            #pragma unroll
            for (int u = 0; u < 4; ++u) {
                const float c = cv[u];
                accLo.x = fmaf(c, bf_lo(pv[u].x), accLo.x);
                accHi.x = fmaf(c, bf_hi(pv[u].x), accHi.x);
                accLo.y = fmaf(c, bf_lo(pv[u].y), accLo.y);
                accHi.y = fmaf(c, bf_hi(pv[u].y), accHi.y);
                accLo.z = fmaf(c, bf_lo(pv[u].z), accLo.z);
                accHi.z = fmaf(c, bf_hi(pv[u].z), accHi.z);
                accLo.w = fmaf(c, bf_lo(pv[u].w), accLo.w);
                accHi.w = fmaf(c, bf_hi(pv[u].w), accHi.w);
            }
        }
        // combine the 2 edge slots (xor 16 — stays within the half)
        accLo.x += __shfl_xor(accLo.x, 16, 64);
        accLo.y += __shfl_xor(accLo.y, 16, 64);
        accLo.z += __shfl_xor(accLo.z, 16, 64);
        accLo.w += __shfl_xor(accLo.w, 16, 64);
        accHi.x += __shfl_xor(accHi.x, 16, 64);
        accHi.y += __shfl_xor(accHi.y, 16, 64);
        accHi.z += __shfl_xor(accHi.z, 16, 64);
        accHi.w += __shfl_xor(accHi.w, 16, 64);
        if (es == 0) {
            // lane ql holds uints u=4*ql..4*ql+3: lo -> cols c0..c0+3, hi -> +16
            const int c0 = (ql >> 2) * 32 + (ql & 3) * 4;
            float4 lo4, hi4;
            lo4.x = accLo.x > 0.f ? accLo.x : 0.01f * accLo.x;
            lo4.y = accLo.y > 0.f ? accLo.y : 0.01f * accLo.y;
            lo4.z = accLo.z > 0.f ? accLo.z : 0.01f * accLo.z;
            lo4.w = accLo.w > 0.f ? accLo.w : 0.01f * accLo.w;
            hi4.x = accHi.x > 0.f ? accHi.x : 0.01f * accHi.x;
            hi4.y = accHi.y > 0.f ? accHi.y : 0.01f * accHi.y;
            hi4.z = accHi.z > 0.f ? accHi.z : 0.01f * accHi.z;
            hi4.w = accHi.w > 0.f ? accHi.w : 0.01f * accHi.w;
            *(float4*)(xout + (size_t)n * FD + c0)      = lo4;
            *(float4*)(xout + (size_t)n * FD + c0 + 16) = hi4;
        }
    } else {
        // generic per-half fallback (rare): 3-pass with max-shift, 32 lanes
        float m = -3.4e38f;
        for (int i = start + l32; i < end; i += 32) m = fmaxf(m, as_[csr_snd[i]]);
        #pragma unroll
        for (int o = 1; o < 32; o <<= 1) m = fmaxf(m, __shfl_xor(m, o, 64));
        float d = 0.f;
        for (int i = start + l32; i < end; i += 32) d += __expf(as_[csr_snd[i]] - m);
        #pragma unroll
        for (int o = 1; o < 32; o <<= 1) d += __shfl_xor(d, o, 64);
        const float inv = (d > 0.f) ? (1.f / d) : 0.f;
        float ax0 = 0.f, ay0 = 0.f, ax1 = 0.f, ay1 = 0.f;
        for (int i = start; i < end; ++i) {
            const int s = csr_snd[i];
            const float coef = __expf(as_[s] - m) * inv;
            const uint2 pv = *(const uint2*)(q_bfu + (size_t)s * 64 + 2 * l32);
            ax0 = fmaf(coef, bf_lo(pv.x), ax0);
            ay0 = fmaf(coef, bf_hi(pv.x), ay0);
            ax1 = fmaf(coef, bf_lo(pv.y), ax1);
            ay1 = fmaf(coef, bf_hi(pv.y), ay1);
        }
        ax0 = ax0 > 0.f ? ax0 : 0.01f * ax0;
        ay0 = ay0 > 0.f ? ay0 : 0.01f * ay0;
        ax1 = ax1 > 0.f ? ax1 : 0.01f * ax1;
        ay1 = ay1 > 0.f ? ay1 : 0.01f * ay1;
        const int u0 = 2 * l32, u1 = u0 + 1;
        const int c00 = (u0 >> 4) * 32 + (u0 & 15);
        const int c10 = (u1 >> 4) * 32 + (u1 & 15);
        xout[(size_t)n * FD + c00]      = ax0;
        xout[(size_t)n * FD + c00 + 16] = ay0;
        xout[(size_t)n * FD + c10]      = ax1;
        xout[(size_t)n * FD + c10 + 16] = ay1;
    }
}

// agg[g] = sum of x rows with gidx==g (gidx sorted -> run-length accumulate)
__global__ __launch_bounds__(256) void agg_kern(
    const float* __restrict__ x, const int* __restrict__ gidx,
    float* __restrict__ agg, int N)
{
    const int c  = threadIdx.x & 127;
    const int rl = threadIdx.x >> 7;   // 0..1
    int n   = blockIdx.x * 128 + rl;
    int end = blockIdx.x * 128 + 128;
    if (end > N) end = N;
    float acc = 0.f; int curg = -1;
    for (; n < end; n += 2) {
        int g = gidx[n];
        if (g != curg) {
            if (curg >= 0) atomAddF(&agg[(size_t)curg * FD + c], acc);
            curg = g; acc = 0.f;
        }
        acc += x[(size_t)n * FD + c];
    }
    if (curg >= 0) atomAddF(&agg[(size_t)curg * FD + c], acc);
}

// g_out = concat([agg, globals]) @ Wg + bg.  One block per graph; 256 thr =
// 2 split-K halves x 128 output cols; Wg reads coalesced across cols.
__global__ __launch_bounds__(256) void glob_kern(
    const float* __restrict__ agg, const float* __restrict__ glb,
    const float* __restrict__ Wg, const float* __restrict__ bg,
    float* __restrict__ gout, int G)
{
    __shared__ float xv[256];
    __shared__ float part[128];
    const int g = blockIdx.x;
    const int t = threadIdx.x;
    if (t < 128) xv[t] = agg[(size_t)g * FD + t];
    else         xv[t] = glb[(size_t)g * FD + (t - 128)];
    __syncthreads();
    const int c = t & 127, half = t >> 7;
    const float* __restrict__ W = Wg + (size_t)half * FD * FD;
    const float* __restrict__ xh = xv + half * FD;
    float acc = 0.f;
    #pragma unroll 8
    for (int k = 0; k < FD; ++k)
        acc = fmaf(xh[k], W[(size_t)k * FD + c], acc);
    if (half == 1) part[c] = acc;
    __syncthreads();
    if (half == 0) gout[(size_t)g * FD + c] = acc + part[c] + bg[c];
}

extern "C" void kernel_launch(void* const* d_in, const int* in_sizes, int n_in,
                              void* d_out, int out_size, void* d_ws, size_t ws_size,
                              hipStream_t stream)
{
    const float* nodes    = (const float*)d_in[0];
    const float* globals_ = (const float*)d_in[1];
    const float* Wq       = (const float*)d_in[2];
    const float* bq       = (const float*)d_in[3];
    const float* Wa       = (const float*)d_in[4];
    const float* ba       = (const float*)d_in[5];  (void)ba;  // cancels in softmax
    const float* Wg       = (const float*)d_in[6];
    const float* bg       = (const float*)d_in[7];
    const int* senders    = (const int*)d_in[8];
    const int* receivers  = (const int*)d_in[9];
    const int* gidx       = (const int*)d_in[10];

    const int N    = in_sizes[0] / FD;
    const int G    = in_sizes[1] / FD;
    const int E    = in_sizes[8];
    const int HOPS = in_sizes[3] / FD;
    const int NB   = (N + 2047) / 2048;   // scan blocks

    // workspace layout
    float* ws = (float*)d_ws;
    size_t off = 0;
    unsigned* q_bfu = (unsigned*)ws;  off += (size_t)N * 64;   // packed bf16 q
    float* xbuf = ws + off;        off += (size_t)N * FD;
    float* agg  = ws + off;        off += (size_t)G * FD;
    float* as_  = ws + off;        off += N;
    int* deg     = (int*)(ws + off); off += N;
    int* rowptr  = (int*)(ws + off); off += N + 1;
    int* cursor  = (int*)(ws + off); off += N;
    int* bsum    = (int*)(ws + off); off += NB;
    int* csr_snd = (int*)(ws + off); off += E;
    off = (off + 3) & ~(size_t)3;                       // 16B-align for short8 loads
    unsigned short* wq_hi = (unsigned short*)(ws + off); off += (size_t)HOPS * 16384 / 2;
    unsigned short* wq_lo = (unsigned short*)(ws + off); off += (size_t)HOPS * 16384 / 2;

    float* xout_final = (float*)d_out;                  // N*FD
    float* gout = (float*)d_out + (size_t)N * FD;       // G*FD

    // ---- one-time prep: W frags + deg zero (fused), CSR, agg zero (fused)
    const int wtot = HOPS * 2048;
    const int wgrid = (((N > wtot) ? N : wtot) + 255) / 256;
    wprep_kern<<<wgrid, 256, 0, stream>>>(Wq, wq_hi, wq_lo, wtot, deg, N);
    hist_kern<<<(E + 255) / 256, 256, 0, stream>>>(receivers, deg, E);
    scan1_kern<<<NB, 256, 0, stream>>>(deg, rowptr, bsum, N);
    scan2_kern<<<1, 64, 0, stream>>>(bsum, rowptr, NB, N, E);
    scan3_kern<<<(N + 255) / 256, 256, 0, stream>>>(rowptr, cursor, bsum, N,
                                                    agg, G * FD);
    fill_kern<<<(E + 255) / 256, 256, 0, stream>>>(senders, receivers, cursor, csr_snd, E);

    const float* xin = nodes;
    for (int h = 0; h < HOPS; ++h) {
        float* xout = (h == HOPS - 1) ? xout_final : xbuf;
        const unsigned short* whi_h = wq_hi + (size_t)h * 16384;
        const unsigned short* wlo_h = wq_lo + (size_t)h * 16384;
        const float* bq_h = bq + (size_t)h * FD;
        const float* Wa_h = Wa + (size_t)h * 2 * FD;

        qkern_mfma<<<(N + 127) / 128, 256, 0, stream>>>(xin, whi_h, wlo_h, bq_h,
                                                        Wa_h, q_bfu, as_, N);
        gat_node_kern<<<(N + 7) / 8, 256, 0, stream>>>(q_bfu, as_, rowptr, csr_snd,
                                                       xout, N);
        xin = xout;
    }

    agg_kern<<<(N + 127) / 128, 256, 0, stream>>>(xin, gidx, agg, N);
    glob_kern<<<G, 256, 0, stream>>>(agg, globals_, Wg, bg, gout, G);
}

// Round 17
// 185.494 us; speedup vs baseline: 1.2147x; 1.0227x over previous
//
#include <hip/hip_runtime.h>
#include <hip/hip_bf16.h>
#include <cstddef>

#define FD 128   // feature dim D == H == 128

typedef __attribute__((ext_vector_type(8))) short short8v;   // 8 bf16 (4 VGPRs)
typedef __attribute__((ext_vector_type(4))) float f32x4;

__device__ __forceinline__ void atomAddF(float* p, float v) {
    unsafeAtomicAdd(p, v);   // HW global_atomic_add_f32 on gfx950
}

__device__ __forceinline__ unsigned short bf16_rne(float x) {
    unsigned u = __float_as_uint(x);
    return (unsigned short)((u + 0x7fffu + ((u >> 16) & 1u)) >> 16);
}

__device__ __forceinline__ float bf_lo(unsigned u) { return __uint_as_float(u << 16); }
__device__ __forceinline__ float bf_hi(unsigned u) { return __uint_as_float(u & 0xffff0000u); }

// ---- one-time W prep (+ deg zeroing folded in): Wq (fp32 [hop][k][col]) ->
// B-fragment-ordered bf16 (single table; W-lo correction dropped — absmax
// evidence R8..R16 shows error is dominated by bf16 q/x rounding, and the
// 15.04 threshold leaves ample margin).  Fragment order:
// [hop][kk(4)][ct(8)][lane(64)][j(8)], element =
// W[kk*32 + (lane>>4)*8 + j][ct*16 + (lane&15)].
__global__ void wprep_kern(const float* __restrict__ Wq,
                           unsigned short* __restrict__ whi, int total,
                           int* __restrict__ deg, int N)
{
    int t = blockIdx.x * blockDim.x + threadIdx.x;
    if (t < N) deg[t] = 0;                  // folded memset (hist runs after)
    if (t >= total) return;                 // total = HOPS*2048
    const int hop = t >> 11;
    const int kk  = (t >> 9) & 3;
    const int ct  = (t >> 6) & 7;
    const int l   = t & 63;
    const float* Wh = Wq + (size_t)hop * FD * FD;
    #pragma unroll
    for (int j = 0; j < 8; ++j) {
        float w = Wh[(size_t)(kk * 32 + (l >> 4) * 8 + j) * FD + ct * 16 + (l & 15)];
        whi[(size_t)t * 8 + j] = bf16_rne(w);
    }
}

// ---- q = xin @ Wq[h] + bq[h] via bf16 MFMA.  A = bf16(x), B = bf16(W)
// (single table).  W fragments LDS-STAGED once per block (32KB -> up to
// 4 blocks/CU); W-reuse: each wave computes 32 rows (two 16-row A strips)
// per B load.  Fused sender-logit as_ = q . Wa[:128]  (receiver term cancels
// in softmax).  q emitted bf16-PACKED: q_bfu[row][u] holds cols
// c0=(u>>4)*32+(u&15) (lo), c0+16 (hi).
// Block: 256 thr = 4 waves; 128 rows/block.
__global__ __launch_bounds__(256) void qkern_mfma(
    const float* __restrict__ xin,
    const unsigned short* __restrict__ whi,
    const float* __restrict__ bq, const float* __restrict__ Wa,
    unsigned* __restrict__ q_bfu, float* __restrict__ as_, int N)
{
    __shared__ unsigned short lds_hi[16384];   // 32KB

    const int t    = threadIdx.x;
    const int lane = t & 63;
    const int w    = t >> 6;                    // wave 0..3
    const int rowBase = blockIdx.x * 128 + w * 32;

    // cooperative stage: 2048 uint4 / 256 thr = 8 trips each
    {
        const uint4* src_hi = (const uint4*)whi;
        uint4* dst_hi = (uint4*)lds_hi;
        #pragma unroll
        for (int i = 0; i < 8; ++i)
            dst_hi[t + i * 256] = src_hi[t + i * 256];
    }
    __syncthreads();
    if (rowBase >= N) return;

    const int kgrp = lane >> 4;                 // 0..3
    const int cidx = lane & 15;

    // A-rows for the two strips (clamped; OOB rows guarded at store)
    int arow0 = rowBase + cidx;       if (arow0 >= N) arow0 = N - 1;
    int arow1 = rowBase + 16 + cidx;  if (arow1 >= N) arow1 = N - 1;
    const float* __restrict__ xr0 = xin + (size_t)arow0 * FD;
    const float* __restrict__ xr1 = xin + (size_t)arow1 * FD;

    f32x4 acc0[8], acc1[8];
    #pragma unroll
    for (int ct = 0; ct < 8; ++ct) {
        acc0[ct] = (f32x4){0.f, 0.f, 0.f, 0.f};
        acc1[ct] = (f32x4){0.f, 0.f, 0.f, 0.f};
    }

    #pragma unroll
    for (int kk = 0; kk < 4; ++kk) {
        const int ko = kk * 32 + kgrp * 8;
        float4 x0a = *(const float4*)(xr0 + ko);
        float4 x0b = *(const float4*)(xr0 + ko + 4);
        float4 x1a = *(const float4*)(xr1 + ko);
        float4 x1b = *(const float4*)(xr1 + ko + 4);
        float v0[8] = {x0a.x, x0a.y, x0a.z, x0a.w, x0b.x, x0b.y, x0b.z, x0b.w};
        float v1[8] = {x1a.x, x1a.y, x1a.z, x1a.w, x1b.x, x1b.y, x1b.z, x1b.w};
        short8v a0, a1;
        #pragma unroll
        for (int j = 0; j < 8; ++j) {
            a0[j] = (short)bf16_rne(v0[j]);
            a1[j] = (short)bf16_rne(v1[j]);
        }
        #pragma unroll
        for (int ct = 0; ct < 8; ++ct) {
            const int fo = ((kk * 8 + ct) * 64 + lane) * 8;
            short8v bhi = *(const short8v*)(lds_hi + fo);
            acc0[ct] = __builtin_amdgcn_mfma_f32_16x16x32_bf16(a0, bhi, acc0[ct], 0, 0, 0);
            acc1[ct] = __builtin_amdgcn_mfma_f32_16x16x32_bf16(a1, bhi, acc1[ct], 0, 0, 0);
        }
    }

    // epilogue: bias, packed-bf16 q store, fused as_ dot — per row strip
    float bqv[8], wav[8];
    #pragma unroll
    for (int ct = 0; ct < 8; ++ct) {
        bqv[ct] = bq[ct * 16 + cidx];
        wav[ct] = Wa[ct * 16 + cidx];
    }
    #pragma unroll
    for (int strip = 0; strip < 2; ++strip) {
        const f32x4* acc = strip ? acc1 : acc0;
        const int sbase = rowBase + strip * 16;
        #pragma unroll
        for (int j = 0; j < 4; ++j) {
            const int row = sbase + kgrp * 4 + j;    // C/D: row=(lane>>4)*4+reg
            const bool ok = row < N;
            float p = 0.f;
            float vv[8];
            #pragma unroll
            for (int ct = 0; ct < 8; ++ct) {
                vv[ct] = acc[ct][j] + bqv[ct];
                p = fmaf(vv[ct], wav[ct], p);
            }
            if (ok) {
                unsigned* qrow = q_bfu + (size_t)row * 64;
                #pragma unroll
                for (int tp = 0; tp < 4; ++tp) {
                    unsigned lo = bf16_rne(vv[2 * tp]);        // col tp*32+cidx
                    unsigned hi = bf16_rne(vv[2 * tp + 1]);    // col tp*32+16+cidx
                    qrow[tp * 16 + cidx] = lo | (hi << 16);
                }
            }
            p += __shfl_xor(p, 1, 64);
            p += __shfl_xor(p, 2, 64);
            p += __shfl_xor(p, 4, 64);
            p += __shfl_xor(p, 8, 64);
            if (ok && cidx == 0) as_[row] = p;
        }
    }
}

// ---------------- CSR build (once; receivers are hop-invariant) -------------
__global__ void hist_kern(const int* __restrict__ rcv, int* __restrict__ deg, int E) {
    int e = blockIdx.x * blockDim.x + threadIdx.x;
    if (e < E) atomicAdd(&deg[rcv[e]], 1);
}

// hierarchical exclusive scan, phase 1: 2048 elems/block, wave-shuffle scan.
__global__ __launch_bounds__(256) void scan1_kern(
    const int* __restrict__ deg, int* __restrict__ rowptr,
    int* __restrict__ bsum, int N)
{
    const int t = threadIdx.x;
    const int base = blockIdx.x * 2048 + t * 8;
    int v[8]; int s = 0;
    #pragma unroll
    for (int j = 0; j < 8; ++j) {
        v[j] = (base + j < N) ? deg[base + j] : 0;
        s += v[j];
    }
    const int lane = t & 63;
    const int wv = t >> 6;   // 0..3
    int incl = s;
    #pragma unroll
    for (int o = 1; o < 64; o <<= 1) {
        int x = __shfl_up(incl, o, 64);
        if (lane >= o) incl += x;
    }
    __shared__ int wsum[4];
    if (lane == 63) wsum[wv] = incl;
    __syncthreads();
    int woff = 0;
    #pragma unroll
    for (int w = 0; w < 4; ++w) woff += (w < wv) ? wsum[w] : 0;
    int excl = woff + incl - s;
    #pragma unroll
    for (int j = 0; j < 8; ++j) {
        if (base + j < N) rowptr[base + j] = excl;
        excl += v[j];
    }
    if (t == 255) bsum[blockIdx.x] = woff + incl;
}

// phase 2: single wave scans block sums (exclusive, in place); writes rowptr[N].
__global__ void scan2_kern(int* __restrict__ bsum, int* __restrict__ rowptr,
                           int nb, int N, int E)
{
    const int lane = threadIdx.x;   // 64 threads
    int carry = 0;
    for (int c = 0; c < nb; c += 64) {
        int i = c + lane;
        int v = (i < nb) ? bsum[i] : 0;
        int incl = v;
        #pragma unroll
        for (int o = 1; o < 64; o <<= 1) {
            int x = __shfl_up(incl, o, 64);
            if (lane >= o) incl += x;
        }
        if (i < nb) bsum[i] = carry + incl - v;
        carry += __shfl(incl, 63, 64);
    }
    if (lane == 0) rowptr[N] = E;
}

// phase 3: add block offsets; fill cursor copy; zero agg (folded memset).
__global__ void scan3_kern(int* __restrict__ rowptr, int* __restrict__ cursor,
                           const int* __restrict__ bsum, int N,
                           float* __restrict__ agg, int aggN)
{
    int i = blockIdx.x * blockDim.x + threadIdx.x;
    if (i < aggN) agg[i] = 0.f;     // agg only written much later (agg_kern)
    if (i >= N) return;
    int v = rowptr[i] + bsum[i >> 11];
    rowptr[i] = v;
    cursor[i] = v;
}

__global__ void fill_kern(const int* __restrict__ snd, const int* __restrict__ rcv,
                          int* __restrict__ cursor, int* __restrict__ csr_snd, int E)
{
    int e = blockIdx.x * blockDim.x + threadIdx.x;
    if (e >= E) return;
    int pos = atomicAdd(&cursor[rcv[e]], 1);
    csr_snd[pos] = snd[e];
}

// ---------------- fused pull-based GAT node update --------------------------
// TWO nodes per wave (one per 32-lane half; 8 nodes / 256-block).  Softmax
// over as_[senders] (receiver terms cancel), no max-shift in the common path
// (logits are O(5); exp cannot overflow).  deg<=32 path: csr/as_ gathered
// once into the half's registers, 5-level in-half reduce.  Feature loop:
// 8 EDGES per trip per node — each lane issues FOUR independent uint4 loads
// (slots es, es+2, es+4, es+6) so a typical deg<=8 node finishes its gather
// in ONE round with 4 loads in flight (R14/R15 lesson: gather depth, not
// instruction count, is the limiter).  1-level combine; float4 stores.
// Per-half 32-lane fallback for deg>32.
__global__ __launch_bounds__(256) void gat_node_kern(
    const unsigned* __restrict__ q_bfu, const float* __restrict__ as_,
    const int* __restrict__ rowptr, const int* __restrict__ csr_snd,
    float* __restrict__ xout, int N)
{
    const int lane = threadIdx.x & 63;
    const int l32  = lane & 31;
    const int base32 = lane & 32;          // 0 or 32 (half base)
    const int n = blockIdx.x * 8 + (threadIdx.x >> 5);
    if (n >= N) return;
    const int start = rowptr[n], end = rowptr[n + 1];
    const int deg = end - start;

    if (deg <= 32) {
        const int i = start + l32;
        const bool valid = i < end;
        const int   s_c = valid ? csr_snd[i] : 0;
        const float e = valid ? __expf(as_[s_c]) : 0.f;
        float d = e;
        #pragma unroll
        for (int o = 1; o < 32; o <<= 1) d += __shfl_xor(d, o, 64);   // in-half
        const float wgt = e * ((d > 0.f) ? (1.f / d) : 0.f);

        const int es = l32 >> 4;       // edge slot within half: 0..1
        const int ql = lane & 15;      // lane within edge group
        float4 accLo = make_float4(0.f, 0.f, 0.f, 0.f);
        float4 accHi = make_float4(0.f, 0.f, 0.f, 0.f);
        for (int kb = 0; kb < deg; kb += 8) {
            int   sv[4];
            float cv[4];
            #pragma unroll
            for (int u = 0; u < 4; ++u) {
                const int k = kb + es + 2 * u;
                const int idx = (k < deg) ? k : (deg - 1);
                sv[u] = __shfl(s_c, base32 + idx, 64);
                cv[u] = __shfl(wgt, base32 + idx, 64);
                if (k >= deg) cv[u] = 0.f;
            }
            uint4 pv[4];
            #pragma unroll
            for (int u = 0; u < 4; ++u)
                pv[u] = *(const uint4*)(q_bfu + (size_t)sv[u] * 64 + 4 * ql);
            #pragma unroll
            for (int u = 0; u < 4; ++u) {
                const float c = cv[u];
                accLo.x = fmaf(c, bf_lo(pv[u].x), accLo.x);
                accHi.x = fmaf(c, bf_hi(pv[u].x), accHi.x);
                accLo.y = fmaf(c, bf_lo(pv[u].y), accLo.y);
                accHi.y = fmaf(c, bf_hi(pv[u].y), accHi.y);
                accLo.z = fmaf(c, bf_lo(pv[u].z), accLo.z);
                accHi.z = fmaf(c, bf_hi(pv[u].z), accHi.z);
                accLo.w = fmaf(c, bf_lo(pv[u].w), accLo.w);
                accHi.w = fmaf(c, bf_hi(pv[u].w), accHi.w);
            }
        }
        // combine the 2 edge slots (xor 16 — stays within the half)
        accLo.x += __shfl_xor(accLo.x, 16, 64);
        accLo.y += __shfl_xor(accLo.y, 16, 64);
        accLo.z += __shfl_xor(accLo.z, 16, 64);
        accLo.w += __shfl_xor(accLo.w, 16, 64);
        accHi.x += __shfl_xor(accHi.x, 16, 64);
        accHi.y += __shfl_xor(accHi.y, 16, 64);
        accHi.z += __shfl_xor(accHi.z, 16, 64);
        accHi.w += __shfl_xor(accHi.w, 16, 64);
        if (es == 0) {
            // lane ql holds uints u=4*ql..4*ql+3: lo -> cols c0..c0+3, hi -> +16
            const int c0 = (ql >> 2) * 32 + (ql & 3) * 4;
            float4 lo4, hi4;
            lo4.x = accLo.x > 0.f ? accLo.x : 0.01f * accLo.x;
            lo4.y = accLo.y > 0.f ? accLo.y : 0.01f * accLo.y;
            lo4.z = accLo.z > 0.f ? accLo.z : 0.01f * accLo.z;
            lo4.w = accLo.w > 0.f ? accLo.w : 0.01f * accLo.w;
            hi4.x = accHi.x > 0.f ? accHi.x : 0.01f * accHi.x;
            hi4.y = accHi.y > 0.f ? accHi.y : 0.01f * accHi.y;
            hi4.z = accHi.z > 0.f ? accHi.z : 0.01f * accHi.z;
            hi4.w = accHi.w > 0.f ? accHi.w : 0.01f * accHi.w;
            *(float4*)(xout + (size_t)n * FD + c0)      = lo4;
            *(float4*)(xout + (size_t)n * FD + c0 + 16) = hi4;
        }
    } else {
        // generic per-half fallback (rare): 3-pass with max-shift, 32 lanes
        float m = -3.4e38f;
        for (int i = start + l32; i < end; i += 32) m = fmaxf(m, as_[csr_snd[i]]);
        #pragma unroll
        for (int o = 1; o < 32; o <<= 1) m = fmaxf(m, __shfl_xor(m, o, 64));
        float d = 0.f;
        for (int i = start + l32; i < end; i += 32) d += __expf(as_[csr_snd[i]] - m);
        #pragma unroll
        for (int o = 1; o < 32; o <<= 1) d += __shfl_xor(d, o, 64);
        const float inv = (d > 0.f) ? (1.f / d) : 0.f;
        float ax0 = 0.f, ay0 = 0.f, ax1 = 0.f, ay1 = 0.f;
        for (int i = start; i < end; ++i) {
            const int s = csr_snd[i];
            const float coef = __expf(as_[s] - m) * inv;
            const uint2 pv = *(const uint2*)(q_bfu + (size_t)s * 64 + 2 * l32);
            ax0 = fmaf(coef, bf_lo(pv.x), ax0);
            ay0 = fmaf(coef, bf_hi(pv.x), ay0);
            ax1 = fmaf(coef, bf_lo(pv.y), ax1);
            ay1 = fmaf(coef, bf_hi(pv.y), ay1);
        }
        ax0 = ax0 > 0.f ? ax0 : 0.01f * ax0;
        ay0 = ay0 > 0.f ? ay0 : 0.01f * ay0;
        ax1 = ax1 > 0.f ? ax1 : 0.01f * ax1;
        ay1 = ay1 > 0.f ? ay1 : 0.01f * ay1;
        const int u0 = 2 * l32, u1 = u0 + 1;
        const int c00 = (u0 >> 4) * 32 + (u0 & 15);
        const int c10 = (u1 >> 4) * 32 + (u1 & 15);
        xout[(size_t)n * FD + c00]      = ax0;
        xout[(size_t)n * FD + c00 + 16] = ay0;
        xout[(size_t)n * FD + c10]      = ax1;
        xout[(size_t)n * FD + c10 + 16] = ay1;
    }
}

// agg[g] = sum of x rows with gidx==g (gidx sorted -> run-length accumulate)
__global__ __launch_bounds__(256) void agg_kern(
    const float* __restrict__ x, const int* __restrict__ gidx,
    float* __restrict__ agg, int N)
{
    const int c  = threadIdx.x & 127;
    const int rl = threadIdx.x >> 7;   // 0..1
    int n   = blockIdx.x * 128 + rl;
    int end = blockIdx.x * 128 + 128;
    if (end > N) end = N;
    float acc = 0.f; int curg = -1;
    for (; n < end; n += 2) {
        int g = gidx[n];
        if (g != curg) {
            if (curg >= 0) atomAddF(&agg[(size_t)curg * FD + c], acc);
            curg = g; acc = 0.f;
        }
        acc += x[(size_t)n * FD + c];
    }
    if (curg >= 0) atomAddF(&agg[(size_t)curg * FD + c], acc);
}

// g_out = concat([agg, globals]) @ Wg + bg.  One block per graph; 256 thr =
// 2 split-K halves x 128 output cols; Wg reads coalesced across cols.
__global__ __launch_bounds__(256) void glob_kern(
    const float* __restrict__ agg, const float* __restrict__ glb,
    const float* __restrict__ Wg, const float* __restrict__ bg,
    float* __restrict__ gout, int G)
{
    __shared__ float xv[256];
    __shared__ float part[128];
    const int g = blockIdx.x;
    const int t = threadIdx.x;
    if (t < 128) xv[t] = agg[(size_t)g * FD + t];
    else         xv[t] = glb[(size_t)g * FD + (t - 128)];
    __syncthreads();
    const int c = t & 127, half = t >> 7;
    const float* __restrict__ W = Wg + (size_t)half * FD * FD;
    const float* __restrict__ xh = xv + half * FD;
    float acc = 0.f;
    #pragma unroll 8
    for (int k = 0; k < FD; ++k)
        acc = fmaf(xh[k], W[(size_t)k * FD + c], acc);
    if (half == 1) part[c] = acc;
    __syncthreads();
    if (half == 0) gout[(size_t)g * FD + c] = acc + part[c] + bg[c];
}

extern "C" void kernel_launch(void* const* d_in, const int* in_sizes, int n_in,
                              void* d_out, int out_size, void* d_ws, size_t ws_size,
                              hipStream_t stream)
{
    const float* nodes    = (const float*)d_in[0];
    const float* globals_ = (const float*)d_in[1];
    const float* Wq       = (const float*)d_in[2];
    const float* bq       = (const float*)d_in[3];
    const float* Wa       = (const float*)d_in[4];
    const float* ba       = (const float*)d_in[5];  (void)ba;  // cancels in softmax
    const float* Wg       = (const float*)d_in[6];
    const float* bg       = (const float*)d_in[7];
    const int* senders    = (const int*)d_in[8];
    const int* receivers  = (const int*)d_in[9];
    const int* gidx       = (const int*)d_in[10];

    const int N    = in_sizes[0] / FD;
    const int G    = in_sizes[1] / FD;
    const int E    = in_sizes[8];
    const int HOPS = in_sizes[3] / FD;
    const int NB   = (N + 2047) / 2048;   // scan blocks

    // workspace layout
    float* ws = (float*)d_ws;
    size_t off = 0;
    unsigned* q_bfu = (unsigned*)ws;  off += (size_t)N * 64;   // packed bf16 q
    float* xbuf = ws + off;        off += (size_t)N * FD;
    float* agg  = ws + off;        off += (size_t)G * FD;
    float* as_  = ws + off;        off += N;
    int* deg     = (int*)(ws + off); off += N;
    int* rowptr  = (int*)(ws + off); off += N + 1;
    int* cursor  = (int*)(ws + off); off += N;
    int* bsum    = (int*)(ws + off); off += NB;
    int* csr_snd = (int*)(ws + off); off += E;
    off = (off + 3) & ~(size_t)3;                       // 16B-align for short8 loads
    unsigned short* wq_hi = (unsigned short*)(ws + off); off += (size_t)HOPS * 16384 / 2;

    float* xout_final = (float*)d_out;                  // N*FD
    float* gout = (float*)d_out + (size_t)N * FD;       // G*FD

    // ---- one-time prep: W frags + deg zero (fused), CSR, agg zero (fused)
    const int wtot = HOPS * 2048;
    const int wgrid = (((N > wtot) ? N : wtot) + 255) / 256;
    wprep_kern<<<wgrid, 256, 0, stream>>>(Wq, wq_hi, wtot, deg, N);
    hist_kern<<<(E + 255) / 256, 256, 0, stream>>>(receivers, deg, E);
    scan1_kern<<<NB, 256, 0, stream>>>(deg, rowptr, bsum, N);
    scan2_kern<<<1, 64, 0, stream>>>(bsum, rowptr, NB, N, E);
    scan3_kern<<<(N + 255) / 256, 256, 0, stream>>>(rowptr, cursor, bsum, N,
                                                    agg, G * FD);
    fill_kern<<<(E + 255) / 256, 256, 0, stream>>>(senders, receivers, cursor, csr_snd, E);

    const float* xin = nodes;
    for (int h = 0; h < HOPS; ++h) {
        float* xout = (h == HOPS - 1) ? xout_final : xbuf;
        const unsigned short* whi_h = wq_hi + (size_t)h * 16384;
        const float* bq_h = bq + (size_t)h * FD;
        const float* Wa_h = Wa + (size_t)h * 2 * FD;

        qkern_mfma<<<(N + 127) / 128, 256, 0, stream>>>(xin, whi_h, bq_h,
                                                        Wa_h, q_bfu, as_, N);
        gat_node_kern<<<(N + 7) / 8, 256, 0, stream>>>(q_bfu, as_, rowptr, csr_snd,
                                                       xout, N);
        xin = xout;
    }

    agg_kern<<<(N + 127) / 128, 256, 0, stream>>>(xin, gidx, agg, N);
    glob_kern<<<G, 256, 0, stream>>>(agg, globals_, Wg, bg, gout, G);
}